// Round 1
// baseline (730.256 us; speedup 1.0000x reference)
//
#include <hip/hip_runtime.h>
#include <hip/hip_bf16.h>
#include <math.h>

// Problem constants
constexpr int B = 128, S = 400, T = 50, H = 512, E = 128, V = 50000, PADV = 1000;
constexpr int NV = V + PADV;        // 51000
constexpr int TH1 = 3 * H + 1;      // 1537

// Output offsets (floats), in reference return order
constexpr int O_PFINAL = 0;                      // B*NV
constexpr int O_PGEN   = O_PFINAL + B * NV;      // B
constexpr int O_PVOCAB = O_PGEN + B;             // B*V
constexpr int O_ATT    = O_PVOCAB + B * V;       // B*S
constexpr int O_DHS    = O_ATT + B * S;          // B*(T+1)*H
constexpr int O_H      = O_DHS + B * (T + 1) * H;// B*H
constexpr int O_NPA    = O_H + B * H;            // B*(T+1)*S

// Workspace offsets (floats)
constexpr int W_X    = 0;                  // B*E gathered embedding
constexpr int W_GX   = W_X + B * E;        // B*3H
constexpr int W_GH   = W_GX + B * 3 * H;   // B*3H
constexpr int W_HW   = W_GH + B * 3 * H;   // B*H  (h * w_h)
constexpr int W_HD   = W_HW + B * H;       // B*H  (h * w_d)
constexpr int W_SC   = W_HD + B * H;       // B*S  att_scores
constexpr int W_DEN  = W_SC + B * S;       // B*S  temporal denominator
constexpr int W_CMB  = W_DEN + B * S;      // B*TH1 combined
constexpr int W_LE   = W_CMB + B * TH1;    // B*E  logits_e
constexpr int W_RMAX = W_LE + B * E;       // B
constexpr int W_RSUM = W_RMAX + B;         // B

__device__ __forceinline__ float wave_sum(float v) {
#pragma unroll
  for (int o = 32; o > 0; o >>= 1) v += __shfl_xor(v, o);
  return v;
}

// ---------------- init: gather emb rows, zero enc-ctx slice of combined, set control
__global__ void k_init(const int* __restrict__ tok, const float* __restrict__ emb,
                       const float* __restrict__ ctrl, float* __restrict__ ws) {
  int i = blockIdx.x * 256 + threadIdx.x;
  if (i < B * E) {
    int b = i >> 7, e = i & 127;
    ws[W_X + i] = emb[tok[b] * E + e];
  }
  if (i < B * H) {
    int b = i >> 9, h = i & 511;
    ws[W_CMB + b * TH1 + H + h] = 0.f;   // encoder_context accumulator
  }
  if (i < B) ws[W_CMB + i * TH1 + 3 * H] = ctrl[i];
}

// ---------------- generic tiled f32 GEMM: C[M][N] = A[M][K] * B[N][K]^T + bias[N]
template <int BM, int BN, int BK, int TM, int TN>
__global__ __launch_bounds__(256) void gemm_abt(
    const float* __restrict__ A, const float* __restrict__ Bm,
    const float* __restrict__ bias, float* __restrict__ C, int M, int N, int K) {
  __shared__ float As[BK][BM + 4];
  __shared__ float Bs[BK][BN + 4];
  const int tid = threadIdx.x;
  const int m0 = blockIdx.y * BM, n0 = blockIdx.x * BN;
  constexpr int TC = BN / TN;
  const int tr = tid / TC, tc = tid % TC;
  float acc[TM][TN] = {};
  for (int k0 = 0; k0 < K; k0 += BK) {
    for (int i = tid; i < BM * BK; i += 256) {
      int m = i / BK, k = i % BK;
      float v = 0.f;
      if (m0 + m < M && k0 + k < K) v = A[(m0 + m) * K + k0 + k];
      As[k][m] = v;
    }
    for (int i = tid; i < BN * BK; i += 256) {
      int n = i / BK, k = i % BK;
      float v = 0.f;
      if (n0 + n < N && k0 + k < K) v = Bm[(n0 + n) * K + k0 + k];
      Bs[k][n] = v;
    }
    __syncthreads();
#pragma unroll
    for (int k = 0; k < BK; ++k) {
      float a[TM], bb[TN];
#pragma unroll
      for (int i = 0; i < TM; ++i) a[i] = As[k][tr * TM + i];
#pragma unroll
      for (int j = 0; j < TN; ++j) bb[j] = Bs[k][tc * TN + j];
#pragma unroll
      for (int i = 0; i < TM; ++i)
#pragma unroll
        for (int j = 0; j < TN; ++j) acc[i][j] += a[i] * bb[j];
    }
    __syncthreads();
  }
#pragma unroll
  for (int i = 0; i < TM; ++i) {
    int m = m0 + tr * TM + i;
    if (m >= M) continue;
#pragma unroll
    for (int j = 0; j < TN; ++j) {
      int n = n0 + tc * TN + j;
      if (n < N) C[m * N + n] = acc[i][j] + bias[n];
    }
  }
}

// ---------------- GRU gates -> h, hw, hd, combined[:,0:H], out h slots
__global__ void k_gates(const float* __restrict__ ws_in, const float* __restrict__ lh,
                        const float* __restrict__ w_h, const float* __restrict__ w_d,
                        float* __restrict__ ws, float* __restrict__ out) {
  int i = blockIdx.x * 256 + threadIdx.x;  // b*H + u
  int b = i >> 9, u = i & 511;
  const float* gx = ws_in + W_GX + b * (3 * H);
  const float* gh = ws_in + W_GH + b * (3 * H);
  float gxr = gx[u], gxz = gx[H + u], gxn = gx[2 * H + u];
  float ghr = gh[u], ghz = gh[H + u], ghn = gh[2 * H + u];
  float r = 1.f / (1.f + __expf(-(gxr + ghr)));
  float z = 1.f / (1.f + __expf(-(gxz + ghz)));
  float n = tanhf(gxn + r * ghn);
  float lhv = lh[i];
  float h = (1.f - z) * n + z * lhv;
  out[O_H + i] = h;
  out[O_DHS + b * ((T + 1) * H) + T * H + u] = h;
  ws[W_CMB + b * TH1 + u] = h;
  ws[W_HW + i] = h * w_h[u];
  ws[W_HD + i] = h * w_d[u];
}

// ---------------- temporal denominator + copy previous_att into new_previous_att
__global__ void k_den(const float* __restrict__ pa, float* __restrict__ ws,
                      float* __restrict__ out) {
  int i = blockIdx.x * 256 + threadIdx.x;
  if (i >= B * S) return;
  int b = i / S, s = i - b * S;
  float acc = 0.f;
  for (int t = 0; t < T; ++t) {
    float v = pa[(b * T + t) * S + s];
    out[O_NPA + (b * (T + 1) + t) * S + s] = v;
    acc += __expf(v);
  }
  ws[W_DEN + i] = acc;
}

// ---------------- attention scores vs encoder (wave per (b,s))
__global__ void k_escore(const float* __restrict__ enc, float* __restrict__ ws,
                         float* __restrict__ out) {
  int blk = blockIdx.x;             // b*25 + sgrp
  int b = blk / 25, sgrp = blk % 25;
  int wave = threadIdx.x >> 6, lane = threadIdx.x & 63;
  const float4* hw4 = (const float4*)(ws + W_HW + b * H);
  float4 h0 = hw4[lane * 2], h1 = hw4[lane * 2 + 1];
#pragma unroll
  for (int ii = 0; ii < 4; ++ii) {
    int s = sgrp * 16 + wave * 4 + ii;
    const float4* e4 = (const float4*)(enc + (b * S + s) * H);
    float4 e0 = e4[lane * 2], e1 = e4[lane * 2 + 1];
    float d = h0.x * e0.x + h0.y * e0.y + h0.z * e0.z + h0.w * e0.w +
              h1.x * e1.x + h1.y * e1.y + h1.z * e1.z + h1.w * e1.w;
    d = wave_sum(d);
    if (lane == 0) {
      ws[W_SC + b * S + s] = d;
      out[O_NPA + (b * (T + 1) + T) * S + s] = d;
    }
  }
}

// ---------------- att_dist (temporal softmax-ish), block per b
__global__ void k_attdist(const float* __restrict__ ws, float* __restrict__ out) {
  int b = blockIdx.x, tid = threadIdx.x;
  __shared__ float red[4];
  int s0 = tid, s1 = tid + 256;
  float t0 = __expf(ws[W_SC + b * S + s0]) / ws[W_DEN + b * S + s0];
  float t1 = 0.f;
  if (s1 < S) t1 = __expf(ws[W_SC + b * S + s1]) / ws[W_DEN + b * S + s1];
  float loc = wave_sum(t0 + t1);
  if ((tid & 63) == 0) red[tid >> 6] = loc;
  __syncthreads();
  float inv = 1.f / (red[0] + red[1] + red[2] + red[3]);
  out[O_ATT + b * S + s0] = t0 * inv;
  if (s1 < S) out[O_ATT + b * S + s1] = t1 * inv;
}

// ---------------- decoder attention: scores, softmax, context, copy prev rows
__global__ void k_dec(const float* __restrict__ pd, float* __restrict__ ws,
                      float* __restrict__ out) {
  int b = blockIdx.x, tid = threadIdx.x;
  int wave = tid >> 6, lane = tid & 63;
  __shared__ float sc[T];
  const float4* hd4 = (const float4*)(ws + W_HD + b * H);
  float4 d0 = hd4[lane * 2], d1 = hd4[lane * 2 + 1];
  for (int t = wave; t < T; t += 4) {
    const float4* p4 = (const float4*)(pd + (b * T + t) * H);
    float4 p0 = p4[lane * 2], p1 = p4[lane * 2 + 1];
    float v = d0.x * p0.x + d0.y * p0.y + d0.z * p0.z + d0.w * p0.w +
              d1.x * p1.x + d1.y * p1.y + d1.z * p1.z + d1.w * p1.w;
    v = wave_sum(v);
    if (lane == 0) sc[t] = v;
  }
  __syncthreads();
  if (tid < 64) {
    float v = (lane < T) ? sc[lane] : -1e30f;
    float m = v;
#pragma unroll
    for (int o = 32; o > 0; o >>= 1) m = fmaxf(m, __shfl_xor(m, o));
    float e = (lane < T) ? __expf(v - m) : 0.f;
    float ssum = wave_sum(e);
    if (lane < T) sc[lane] = e / ssum;
  }
  __syncthreads();
  float a0 = 0.f, a1 = 0.f;
  int h0 = tid, h1 = tid + 256;
  for (int t = 0; t < T; ++t) {
    float wt = sc[t];
    a0 += wt * pd[(b * T + t) * H + h0];
    a1 += wt * pd[(b * T + t) * H + h1];
  }
  ws[W_CMB + b * TH1 + 2 * H + h0] = a0;
  ws[W_CMB + b * TH1 + 2 * H + h1] = a1;
  // copy prev decoder states into output rows [0..T)
  const float4* src = (const float4*)(pd + b * T * H);
  float4* dst = (float4*)(out + O_DHS + b * (T + 1) * H);
  for (int i = tid; i < T * H / 4; i += 256) dst[i] = src[i];
}

// ---------------- encoder context: (b, s-chunk) partial + atomic accumulate
__global__ void k_encctx(const float* __restrict__ enc, const float* __restrict__ out,
                         float* __restrict__ ws) {
  int blk = blockIdx.x;
  int b = blk / 5, c = blk % 5;
  int s0 = c * 80, tid = threadIdx.x;
  __shared__ float ad[80];
  if (tid < 80) ad[tid] = out[O_ATT + b * S + s0 + tid];
  __syncthreads();
  float a0 = 0.f, a1 = 0.f;
  int h0 = tid, h1 = tid + 256;
  for (int j = 0; j < 80; ++j) {
    float w = ad[j];
    const float* ep = enc + (b * S + s0 + j) * H;
    a0 += w * ep[h0];
    a1 += w * ep[h1];
  }
  atomicAdd(&ws[W_CMB + b * TH1 + H + h0], a0);
  atomicAdd(&ws[W_CMB + b * TH1 + H + h1], a1);
}

// ---------------- logits_e = combined @ outh_W^T + outh_b   (2 batches per block)
__global__ void k_outh(const float* __restrict__ oW, const float* __restrict__ ob,
                       float* __restrict__ ws) {
  __shared__ float cmb[2 * TH1];
  int tid = threadIdx.x;
  int b0 = blockIdx.x * 2;
  for (int i = tid; i < 2 * TH1; i += 256) cmb[i] = ws[W_CMB + b0 * TH1 + i];
  __syncthreads();
  int half = tid >> 7, e = tid & 127;
  const float* wrow = oW + e * TH1;
  const float* c = cmb + half * TH1;
  float acc = ob[e];
  for (int k = 0; k < TH1; ++k) acc += wrow[k] * c[k];
  ws[W_LE + (b0 + half) * E + e] = acc;
}

// ---------------- p_gen (one wave per b)
__global__ void k_gen(const float* __restrict__ gW, const float* __restrict__ gb,
                      const float* __restrict__ ws, float* __restrict__ out) {
  int b = blockIdx.x, lane = threadIdx.x;
  float acc = 0.f;
  for (int k = lane; k < TH1; k += 64) acc += gW[k] * ws[W_CMB + b * TH1 + k];
  acc = wave_sum(acc);
  if (lane == 0) out[O_PGEN + b] = 1.f / (1.f + __expf(-(acc + gb[0])));
}

// ---------------- vocab softmax pass 1: online row max/sum (block per b)
__global__ void k_rowstat(const float* __restrict__ out, float* __restrict__ ws) {
  int b = blockIdx.x, tid = threadIdx.x;
  const float4* l4 = (const float4*)(out + O_PVOCAB + b * V);
  float m = -1e30f, ssum = 0.f;
  for (int i = tid; i < V / 4; i += 256) {
    float4 v = l4[i];
    float mm = fmaxf(fmaxf(v.x, v.y), fmaxf(v.z, v.w));
    if (mm > m) { ssum *= __expf(m - mm); m = mm; }
    ssum += __expf(v.x - m) + __expf(v.y - m) + __expf(v.z - m) + __expf(v.w - m);
  }
  __shared__ float mred[4], sred[4];
#pragma unroll
  for (int o = 32; o > 0; o >>= 1) {
    float om = __shfl_xor(m, o), os = __shfl_xor(ssum, o);
    float nm = fmaxf(m, om);
    ssum = ssum * __expf(m - nm) + os * __expf(om - nm);
    m = nm;
  }
  if ((tid & 63) == 0) { mred[tid >> 6] = m; sred[tid >> 6] = ssum; }
  __syncthreads();
  if (tid == 0) {
    float M = mred[0], SS = sred[0];
    for (int w = 1; w < 4; ++w) {
      float nm = fmaxf(M, mred[w]);
      SS = SS * __expf(M - nm) + sred[w] * __expf(mred[w] - nm);
      M = nm;
    }
    ws[W_RMAX + b] = M;
    ws[W_RSUM + b] = SS;
  }
}

// ---------------- vocab softmax pass 2: p_vocab (in place) + p_final main region
__global__ void k_pvocab(const float* __restrict__ ws, float* __restrict__ out) {
  int b = blockIdx.y;
  int i = blockIdx.x * 256 + threadIdx.x;
  if (i >= V / 4) return;
  float m = ws[W_RMAX + b], inv = 1.f / ws[W_RSUM + b];
  float pg = out[O_PGEN + b];
  float4 v = ((const float4*)(out + O_PVOCAB + b * V))[i];
  float4 p;
  p.x = __expf(v.x - m) * inv;
  p.y = __expf(v.y - m) * inv;
  p.z = __expf(v.z - m) * inv;
  p.w = __expf(v.w - m) * inv;
  ((float4*)(out + O_PVOCAB + b * V))[i] = p;
  float4 pf;
  pf.x = pg * p.x; pf.y = pg * p.y; pf.z = pg * p.z; pf.w = pg * p.w;
  ((float4*)(out + O_PFINAL + b * NV))[i] = pf;
}

// ---------------- zero pad region of p_final
__global__ void k_pad(float* __restrict__ out) {
  int i = blockIdx.x * 256 + threadIdx.x;
  if (i >= B * PADV / 4) return;
  int b = i / (PADV / 4), j = i % (PADV / 4);
  ((float4*)(out + O_PFINAL + b * NV + V))[j] = make_float4(0.f, 0.f, 0.f, 0.f);
}

// ---------------- scatter (1-p_gen)*att_dist into p_final
__global__ void k_scatter(const int* __restrict__ fiv, float* __restrict__ out) {
  int i = blockIdx.x * 256 + threadIdx.x;
  if (i >= B * S) return;
  int b = i / S;
  int idx = fiv[i];
  float pg = out[O_PGEN + b];
  float val = (1.f - pg) * out[O_ATT + i];
  atomicAdd(out + O_PFINAL + b * NV + idx, val);
}

extern "C" void kernel_launch(void* const* d_in, const int* in_sizes, int n_in,
                              void* d_out, int out_size, void* d_ws, size_t ws_size,
                              hipStream_t stream) {
  const int*   tok  = (const int*)d_in[0];
  const float* pd   = (const float*)d_in[1];
  const float* lh   = (const float*)d_in[2];
  const float* enc  = (const float*)d_in[3];
  const int*   fiv  = (const int*)d_in[4];
  const float* pa   = (const float*)d_in[5];
  const float* ctrl = (const float*)d_in[6];
  const float* emb  = (const float*)d_in[7];
  const float* W_ih = (const float*)d_in[8];
  const float* W_hh = (const float*)d_in[9];
  const float* b_ih = (const float*)d_in[10];
  const float* b_hh = (const float*)d_in[11];
  const float* w_h  = (const float*)d_in[12];
  const float* w_d  = (const float*)d_in[13];
  const float* gW   = (const float*)d_in[14];
  const float* gb   = (const float*)d_in[15];
  const float* ohW  = (const float*)d_in[16];
  const float* ohb  = (const float*)d_in[17];
  const float* ovW  = (const float*)d_in[18];
  const float* ovb  = (const float*)d_in[19];
  float* out = (float*)d_out;
  float* ws  = (float*)d_ws;

  k_init<<<256, 256, 0, stream>>>(tok, emb, ctrl, ws);
  gemm_abt<64, 64, 32, 4, 4><<<dim3(24, 2), 256, 0, stream>>>(ws + W_X, W_ih, b_ih, ws + W_GX, B, 3 * H, E);
  gemm_abt<64, 64, 32, 4, 4><<<dim3(24, 2), 256, 0, stream>>>(lh, W_hh, b_hh, ws + W_GH, B, 3 * H, H);
  k_gates<<<256, 256, 0, stream>>>(ws, lh, w_h, w_d, ws, out);
  k_den<<<200, 256, 0, stream>>>(pa, ws, out);
  k_escore<<<3200, 256, 0, stream>>>(enc, ws, out);
  k_attdist<<<128, 256, 0, stream>>>(ws, out);
  k_dec<<<128, 256, 0, stream>>>(pd, ws, out);
  k_encctx<<<640, 256, 0, stream>>>(enc, out, ws);
  k_outh<<<64, 256, 0, stream>>>(ohW, ohb, ws);
  k_gen<<<128, 64, 0, stream>>>(gW, gb, ws, out);
  gemm_abt<128, 64, 32, 8, 4><<<dim3((V + 63) / 64, 1), 256, 0, stream>>>(ws + W_LE, ovW, ovb, out + O_PVOCAB, B, V, E);
  k_rowstat<<<128, 256, 0, stream>>>(out, ws);
  k_pvocab<<<dim3(49, 128), 256, 0, stream>>>(ws, out);
  k_pad<<<125, 256, 0, stream>>>(out);
  k_scatter<<<200, 256, 0, stream>>>(fiv, out);
}

// Round 3
// 560.832 us; speedup vs baseline: 1.3021x; 1.3021x over previous
//
#include <hip/hip_runtime.h>
#include <hip/hip_bf16.h>
#include <math.h>

// Problem constants
constexpr int B = 128, S = 400, T = 50, H = 512, E = 128, V = 50000, PADV = 1000;
constexpr int NV = V + PADV;        // 51000
constexpr int TH1 = 3 * H + 1;      // 1537

// Output offsets (floats), in reference return order
constexpr int O_PFINAL = 0;                      // B*NV
constexpr int O_PGEN   = O_PFINAL + B * NV;      // B
constexpr int O_PVOCAB = O_PGEN + B;             // B*V
constexpr int O_ATT    = O_PVOCAB + B * V;       // B*S
constexpr int O_DHS    = O_ATT + B * S;          // B*(T+1)*H
constexpr int O_H      = O_DHS + B * (T + 1) * H;// B*H
constexpr int O_NPA    = O_H + B * H;            // B*(T+1)*S

// Workspace offsets (floats)
constexpr int W_X    = 0;                  // B*E gathered embedding
constexpr int W_GX   = W_X + B * E;        // B*3H
constexpr int W_GH   = W_GX + B * 3 * H;   // B*3H
constexpr int W_HW   = W_GH + B * 3 * H;   // B*H  (h * w_h)
constexpr int W_HD   = W_HW + B * H;       // B*H  (h * w_d)
constexpr int W_SC   = W_HD + B * H;       // B*S  att_scores
constexpr int W_DEN  = W_SC + B * S;       // B*S  temporal denominator
constexpr int W_CMB  = W_DEN + B * S;      // B*TH1 combined
constexpr int W_LE   = W_CMB + B * TH1;    // B*E  logits_e
constexpr int W_RMAX = W_LE + B * E;       // B
constexpr int W_RSUM = W_RMAX + B;         // B
constexpr int W_PM   = W_RSUM + B;         // B*10 partial max
constexpr int W_PS   = W_PM + B * 10;      // B*10 partial sum

__device__ __forceinline__ float wave_sum(float v) {
#pragma unroll
  for (int o = 32; o > 0; o >>= 1) v += __shfl_xor(v, o);
  return v;
}

// ---------------- init: gather emb rows, zero enc-ctx slice of combined, set control
__global__ void k_init(const int* __restrict__ tok, const float* __restrict__ emb,
                       const float* __restrict__ ctrl, float* __restrict__ ws) {
  int i = blockIdx.x * 256 + threadIdx.x;
  if (i < B * E) {
    int b = i >> 7, e = i & 127;
    ws[W_X + i] = emb[tok[b] * E + e];
  }
  if (i < B * H) {
    int b = i >> 9, h = i & 511;
    ws[W_CMB + b * TH1 + H + h] = 0.f;   // encoder_context accumulator
  }
  if (i < B) ws[W_CMB + i * TH1 + 3 * H] = ctrl[i];
}

// ---------------- generic tiled f32 GEMM: C[M][N] = A[M][K] * B[N][K]^T + bias[N]
template <int BM, int BN, int BK, int TM, int TN>
__global__ __launch_bounds__(256) void gemm_abt(
    const float* __restrict__ A, const float* __restrict__ Bm,
    const float* __restrict__ bias, float* __restrict__ C, int M, int N, int K) {
  __shared__ float As[BK][BM + 4];
  __shared__ float Bs[BK][BN + 4];
  const int tid = threadIdx.x;
  const int m0 = blockIdx.y * BM, n0 = blockIdx.x * BN;
  constexpr int TC = BN / TN;
  const int tr = tid / TC, tc = tid % TC;
  float acc[TM][TN] = {};
  for (int k0 = 0; k0 < K; k0 += BK) {
    for (int i = tid; i < BM * BK; i += 256) {
      int m = i / BK, k = i % BK;
      float v = 0.f;
      if (m0 + m < M && k0 + k < K) v = A[(m0 + m) * K + k0 + k];
      As[k][m] = v;
    }
    for (int i = tid; i < BN * BK; i += 256) {
      int n = i / BK, k = i % BK;
      float v = 0.f;
      if (n0 + n < N && k0 + k < K) v = Bm[(n0 + n) * K + k0 + k];
      Bs[k][n] = v;
    }
    __syncthreads();
#pragma unroll
    for (int k = 0; k < BK; ++k) {
      float a[TM], bb[TN];
#pragma unroll
      for (int i = 0; i < TM; ++i) a[i] = As[k][tr * TM + i];
#pragma unroll
      for (int j = 0; j < TN; ++j) bb[j] = Bs[k][tc * TN + j];
#pragma unroll
      for (int i = 0; i < TM; ++i)
#pragma unroll
        for (int j = 0; j < TN; ++j) acc[i][j] += a[i] * bb[j];
    }
    __syncthreads();
  }
#pragma unroll
  for (int i = 0; i < TM; ++i) {
    int m = m0 + tr * TM + i;
    if (m >= M) continue;
#pragma unroll
    for (int j = 0; j < TN; ++j) {
      int n = n0 + tc * TN + j;
      if (n < N) C[m * N + n] = acc[i][j] + bias[n];
    }
  }
}

// ---------------- GRU gates -> h, hw, hd, combined[:,0:H], out h slots
__global__ void k_gates(const float* __restrict__ ws_in, const float* __restrict__ lh,
                        const float* __restrict__ w_h, const float* __restrict__ w_d,
                        float* __restrict__ ws, float* __restrict__ out) {
  int i = blockIdx.x * 256 + threadIdx.x;  // b*H + u
  int b = i >> 9, u = i & 511;
  const float* gx = ws_in + W_GX + b * (3 * H);
  const float* gh = ws_in + W_GH + b * (3 * H);
  float gxr = gx[u], gxz = gx[H + u], gxn = gx[2 * H + u];
  float ghr = gh[u], ghz = gh[H + u], ghn = gh[2 * H + u];
  float r = 1.f / (1.f + __expf(-(gxr + ghr)));
  float z = 1.f / (1.f + __expf(-(gxz + ghz)));
  float n = tanhf(gxn + r * ghn);
  float lhv = lh[i];
  float h = (1.f - z) * n + z * lhv;
  out[O_H + i] = h;
  out[O_DHS + b * ((T + 1) * H) + T * H + u] = h;
  ws[W_CMB + b * TH1 + u] = h;
  ws[W_HW + i] = h * w_h[u];
  ws[W_HD + i] = h * w_d[u];
}

// ---------------- temporal denominator + copy previous_att into new_previous_att
__global__ void k_den(const float* __restrict__ pa, float* __restrict__ ws,
                      float* __restrict__ out) {
  int i = blockIdx.x * 256 + threadIdx.x;
  if (i >= B * S) return;
  int b = i / S, s = i - b * S;
  float acc = 0.f;
  for (int t = 0; t < T; ++t) {
    float v = pa[(b * T + t) * S + s];
    out[O_NPA + (b * (T + 1) + t) * S + s] = v;
    acc += __expf(v);
  }
  ws[W_DEN + i] = acc;
}

// ---------------- attention scores vs encoder (wave per (b,s))
__global__ void k_escore(const float* __restrict__ enc, float* __restrict__ ws,
                         float* __restrict__ out) {
  int blk = blockIdx.x;             // b*25 + sgrp
  int b = blk / 25, sgrp = blk % 25;
  int wave = threadIdx.x >> 6, lane = threadIdx.x & 63;
  const float4* hw4 = (const float4*)(ws + W_HW + b * H);
  float4 h0 = hw4[lane * 2], h1 = hw4[lane * 2 + 1];
#pragma unroll
  for (int ii = 0; ii < 4; ++ii) {
    int s = sgrp * 16 + wave * 4 + ii;
    const float4* e4 = (const float4*)(enc + (b * S + s) * H);
    float4 e0 = e4[lane * 2], e1 = e4[lane * 2 + 1];
    float d = h0.x * e0.x + h0.y * e0.y + h0.z * e0.z + h0.w * e0.w +
              h1.x * e1.x + h1.y * e1.y + h1.z * e1.z + h1.w * e1.w;
    d = wave_sum(d);
    if (lane == 0) {
      ws[W_SC + b * S + s] = d;
      out[O_NPA + (b * (T + 1) + T) * S + s] = d;
    }
  }
}

// ---------------- att_dist (temporal softmax-ish), block per b
__global__ void k_attdist(const float* __restrict__ ws, float* __restrict__ out) {
  int b = blockIdx.x, tid = threadIdx.x;
  __shared__ float red[4];
  int s0 = tid, s1 = tid + 256;
  float t0 = __expf(ws[W_SC + b * S + s0]) / ws[W_DEN + b * S + s0];
  float t1 = 0.f;
  if (s1 < S) t1 = __expf(ws[W_SC + b * S + s1]) / ws[W_DEN + b * S + s1];
  float loc = wave_sum(t0 + t1);
  if ((tid & 63) == 0) red[tid >> 6] = loc;
  __syncthreads();
  float inv = 1.f / (red[0] + red[1] + red[2] + red[3]);
  out[O_ATT + b * S + s0] = t0 * inv;
  if (s1 < S) out[O_ATT + b * S + s1] = t1 * inv;
}

// ---------------- decoder attention: scores, softmax, context, copy prev rows
__global__ void k_dec(const float* __restrict__ pd, float* __restrict__ ws,
                      float* __restrict__ out) {
  int b = blockIdx.x, tid = threadIdx.x;
  int wave = tid >> 6, lane = tid & 63;
  __shared__ float sc[T];
  const float4* hd4 = (const float4*)(ws + W_HD + b * H);
  float4 d0 = hd4[lane * 2], d1 = hd4[lane * 2 + 1];
  for (int t = wave; t < T; t += 4) {
    const float4* p4 = (const float4*)(pd + (b * T + t) * H);
    float4 p0 = p4[lane * 2], p1 = p4[lane * 2 + 1];
    float v = d0.x * p0.x + d0.y * p0.y + d0.z * p0.z + d0.w * p0.w +
              d1.x * p1.x + d1.y * p1.y + d1.z * p1.z + d1.w * p1.w;
    v = wave_sum(v);
    if (lane == 0) sc[t] = v;
  }
  __syncthreads();
  if (tid < 64) {
    float v = (lane < T) ? sc[lane] : -1e30f;
    float m = v;
#pragma unroll
    for (int o = 32; o > 0; o >>= 1) m = fmaxf(m, __shfl_xor(m, o));
    float e = (lane < T) ? __expf(v - m) : 0.f;
    float ssum = wave_sum(e);
    if (lane < T) sc[lane] = e / ssum;
  }
  __syncthreads();
  float a0 = 0.f, a1 = 0.f;
  int h0 = tid, h1 = tid + 256;
  for (int t = 0; t < T; ++t) {
    float wt = sc[t];
    a0 += wt * pd[(b * T + t) * H + h0];
    a1 += wt * pd[(b * T + t) * H + h1];
  }
  ws[W_CMB + b * TH1 + 2 * H + h0] = a0;
  ws[W_CMB + b * TH1 + 2 * H + h1] = a1;
  // copy prev decoder states into output rows [0..T)
  const float4* src = (const float4*)(pd + b * T * H);
  float4* dst = (float4*)(out + O_DHS + b * (T + 1) * H);
  for (int i = tid; i < T * H / 4; i += 256) dst[i] = src[i];
}

// ---------------- encoder context: (b, s-chunk) partial + atomic accumulate
__global__ void k_encctx(const float* __restrict__ enc, const float* __restrict__ out,
                         float* __restrict__ ws) {
  int blk = blockIdx.x;
  int b = blk / 5, c = blk % 5;
  int s0 = c * 80, tid = threadIdx.x;
  __shared__ float ad[80];
  if (tid < 80) ad[tid] = out[O_ATT + b * S + s0 + tid];
  __syncthreads();
  float a0 = 0.f, a1 = 0.f;
  int h0 = tid, h1 = tid + 256;
  for (int j = 0; j < 80; ++j) {
    float w = ad[j];
    const float* ep = enc + (b * S + s0 + j) * H;
    a0 += w * ep[h0];
    a1 += w * ep[h1];
  }
  atomicAdd(&ws[W_CMB + b * TH1 + H + h0], a0);
  atomicAdd(&ws[W_CMB + b * TH1 + H + h1], a1);
}

// ---------------- logits_e = combined @ outh_W^T + outh_b
// wave-per-e, 8 b-rows staged in LDS, outh_W row held in registers.
// grid (32, 16): x = e-group (4 e per block, 1 per wave), y = b-group (8 b).
__global__ __launch_bounds__(256) void k_outh2(const float* __restrict__ oW,
                                               const float* __restrict__ ob,
                                               float* __restrict__ ws) {
  __shared__ float cmb[8 * TH1];
  const int tid = threadIdx.x;
  const int b0 = blockIdx.y * 8;
  const int e = blockIdx.x * 4 + (tid >> 6);
  const int lane = tid & 63;
  // contiguous copy of 8 combined rows into LDS (coalesced)
  const float* src = ws + W_CMB + b0 * TH1;
  for (int i = tid; i < 8 * TH1; i += 256) cmb[i] = src[i];
  // outh_W row -> registers (coalesced: lanes read consecutive k)
  float wr[25];
  const float* wrow = oW + e * TH1;
#pragma unroll
  for (int j = 0; j < 25; ++j) {
    int k = lane + 64 * j;
    wr[j] = (k < TH1) ? wrow[k] : 0.f;
  }
  __syncthreads();
  float bias = ob[e];
#pragma unroll 1
  for (int bb = 0; bb < 8; ++bb) {
    const float* c = cmb + bb * TH1;
    float a = 0.f;
#pragma unroll
    for (int j = 0; j < 25; ++j) {
      int k = lane + 64 * j;
      float cv = (k < TH1) ? c[k] : 0.f;
      a += wr[j] * cv;
    }
    a = wave_sum(a);
    if (lane == 0) ws[W_LE + (b0 + bb) * E + e] = a + bias;
  }
}

// ---------------- p_gen (one wave per b)
__global__ void k_gen(const float* __restrict__ gW, const float* __restrict__ gb,
                      const float* __restrict__ ws, float* __restrict__ out) {
  int b = blockIdx.x, lane = threadIdx.x;
  float acc = 0.f;
  for (int k = lane; k < TH1; k += 64) acc += gW[k] * ws[W_CMB + b * TH1 + k];
  acc = wave_sum(acc);
  if (lane == 0) out[O_PGEN + b] = 1.f / (1.f + __expf(-(acc + gb[0])));
}

// ---------------- vocab softmax pass 1a: partial max/sum per (b, chunk)
// grid (10, 128): chunk c covers float4 indices [c*1250, (c+1)*1250)
__global__ void k_rowstat1(const float* __restrict__ out, float* __restrict__ ws) {
  int c = blockIdx.x, b = blockIdx.y, tid = threadIdx.x;
  const float4* l4 = (const float4*)(out + O_PVOCAB + b * V);
  int base = c * 1250;
  float m = -1e30f, ssum = 0.f;
  for (int i = base + tid; i < base + 1250; i += 256) {
    float4 v = l4[i];
    float mm = fmaxf(fmaxf(v.x, v.y), fmaxf(v.z, v.w));
    if (mm > m) { ssum *= __expf(m - mm); m = mm; }
    ssum += __expf(v.x - m) + __expf(v.y - m) + __expf(v.z - m) + __expf(v.w - m);
  }
  __shared__ float mred[4], sred[4];
#pragma unroll
  for (int o = 32; o > 0; o >>= 1) {
    float om = __shfl_xor(m, o), os = __shfl_xor(ssum, o);
    float nm = fmaxf(m, om);
    ssum = ssum * __expf(m - nm) + os * __expf(om - nm);
    m = nm;
  }
  if ((tid & 63) == 0) { mred[tid >> 6] = m; sred[tid >> 6] = ssum; }
  __syncthreads();
  if (tid == 0) {
    float M = mred[0], SS = sred[0];
    for (int w = 1; w < 4; ++w) {
      float nm = fmaxf(M, mred[w]);
      SS = SS * __expf(M - nm) + sred[w] * __expf(mred[w] - nm);
      M = nm;
    }
    ws[W_PM + b * 10 + c] = M;
    ws[W_PS + b * 10 + c] = SS;
  }
}

// ---------------- vocab softmax pass 1b: combine 10 partials per b
__global__ void k_rowstat2(float* __restrict__ ws) {
  int b = threadIdx.x;  // 128 threads
  float M = -1e30f;
#pragma unroll
  for (int c = 0; c < 10; ++c) M = fmaxf(M, ws[W_PM + b * 10 + c]);
  float SS = 0.f;
#pragma unroll
  for (int c = 0; c < 10; ++c) SS += ws[W_PS + b * 10 + c] * __expf(ws[W_PM + b * 10 + c] - M);
  ws[W_RMAX + b] = M;
  ws[W_RSUM + b] = SS;
}

// ---------------- vocab softmax pass 2: p_vocab (in place) + p_final main region
__global__ void k_pvocab(const float* __restrict__ ws, float* __restrict__ out) {
  int b = blockIdx.y;
  int i = blockIdx.x * 256 + threadIdx.x;
  if (i >= V / 4) return;
  float m = ws[W_RMAX + b], inv = 1.f / ws[W_RSUM + b];
  float pg = out[O_PGEN + b];
  float4 v = ((const float4*)(out + O_PVOCAB + b * V))[i];
  float4 p;
  p.x = __expf(v.x - m) * inv;
  p.y = __expf(v.y - m) * inv;
  p.z = __expf(v.z - m) * inv;
  p.w = __expf(v.w - m) * inv;
  ((float4*)(out + O_PVOCAB + b * V))[i] = p;
  float4 pf;
  pf.x = pg * p.x; pf.y = pg * p.y; pf.z = pg * p.z; pf.w = pg * p.w;
  ((float4*)(out + O_PFINAL + b * NV))[i] = pf;
}

// ---------------- zero pad region of p_final
__global__ void k_pad(float* __restrict__ out) {
  int i = blockIdx.x * 256 + threadIdx.x;
  if (i >= B * PADV / 4) return;
  int b = i / (PADV / 4), j = i % (PADV / 4);
  ((float4*)(out + O_PFINAL + b * NV + V))[j] = make_float4(0.f, 0.f, 0.f, 0.f);
}

// ---------------- scatter (1-p_gen)*att_dist into p_final
__global__ void k_scatter(const int* __restrict__ fiv, float* __restrict__ out) {
  int i = blockIdx.x * 256 + threadIdx.x;
  if (i >= B * S) return;
  int b = i / S;
  int idx = fiv[i];
  float pg = out[O_PGEN + b];
  float val = (1.f - pg) * out[O_ATT + i];
  atomicAdd(out + O_PFINAL + b * NV + idx, val);
}

extern "C" void kernel_launch(void* const* d_in, const int* in_sizes, int n_in,
                              void* d_out, int out_size, void* d_ws, size_t ws_size,
                              hipStream_t stream) {
  const int*   tok  = (const int*)d_in[0];
  const float* pd   = (const float*)d_in[1];
  const float* lh   = (const float*)d_in[2];
  const float* enc  = (const float*)d_in[3];
  const int*   fiv  = (const int*)d_in[4];
  const float* pa   = (const float*)d_in[5];
  const float* ctrl = (const float*)d_in[6];
  const float* emb  = (const float*)d_in[7];
  const float* W_ih = (const float*)d_in[8];
  const float* W_hh = (const float*)d_in[9];
  const float* b_ih = (const float*)d_in[10];
  const float* b_hh = (const float*)d_in[11];
  const float* w_h  = (const float*)d_in[12];
  const float* w_d  = (const float*)d_in[13];
  const float* gW   = (const float*)d_in[14];
  const float* gb   = (const float*)d_in[15];
  const float* ohW  = (const float*)d_in[16];
  const float* ohb  = (const float*)d_in[17];
  const float* ovW  = (const float*)d_in[18];
  const float* ovb  = (const float*)d_in[19];
  float* out = (float*)d_out;
  float* ws  = (float*)d_ws;

  k_init<<<256, 256, 0, stream>>>(tok, emb, ctrl, ws);
  gemm_abt<64, 64, 32, 4, 4><<<dim3(24, 2), 256, 0, stream>>>(ws + W_X, W_ih, b_ih, ws + W_GX, B, 3 * H, E);
  gemm_abt<64, 64, 32, 4, 4><<<dim3(24, 2), 256, 0, stream>>>(lh, W_hh, b_hh, ws + W_GH, B, 3 * H, H);
  k_gates<<<256, 256, 0, stream>>>(ws, lh, w_h, w_d, ws, out);
  k_den<<<200, 256, 0, stream>>>(pa, ws, out);
  k_escore<<<3200, 256, 0, stream>>>(enc, ws, out);
  k_attdist<<<128, 256, 0, stream>>>(ws, out);
  k_dec<<<128, 256, 0, stream>>>(pd, ws, out);
  k_encctx<<<640, 256, 0, stream>>>(enc, out, ws);
  k_outh2<<<dim3(32, 16), 256, 0, stream>>>(ohW, ohb, ws);
  k_gen<<<128, 64, 0, stream>>>(gW, gb, ws, out);
  gemm_abt<128, 64, 32, 8, 4><<<dim3((V + 63) / 64, 1), 256, 0, stream>>>(ws + W_LE, ovW, ovb, out + O_PVOCAB, B, V, E);
  k_rowstat1<<<dim3(10, 128), 256, 0, stream>>>(out, ws);
  k_rowstat2<<<1, 128, 0, stream>>>(ws);
  k_pvocab<<<dim3(49, 128), 256, 0, stream>>>(ws, out);
  k_pad<<<125, 256, 0, stream>>>(out);
  k_scatter<<<200, 256, 0, stream>>>(fiv, out);
}

// Round 4
// 415.730 us; speedup vs baseline: 1.7566x; 1.3490x over previous
//
#include <hip/hip_runtime.h>
#include <hip/hip_bf16.h>
#include <math.h>

// Problem constants
constexpr int B = 128, S = 400, T = 50, H = 512, E = 128, V = 50000, PADV = 1000;
constexpr int NV = V + PADV;        // 51000
constexpr int TH1 = 3 * H + 1;      // 1537

// Output offsets (floats), in reference return order
constexpr int O_PFINAL = 0;                      // B*NV
constexpr int O_PGEN   = O_PFINAL + B * NV;      // B
constexpr int O_PVOCAB = O_PGEN + B;             // B*V
constexpr int O_ATT    = O_PVOCAB + B * V;       // B*S
constexpr int O_DHS    = O_ATT + B * S;          // B*(T+1)*H
constexpr int O_H      = O_DHS + B * (T + 1) * H;// B*H
constexpr int O_NPA    = O_H + B * H;            // B*(T+1)*S

// Workspace offsets (floats)
constexpr int W_X    = 0;                  // B*E gathered embedding
constexpr int W_GX   = W_X + B * E;        // B*3H  (raw x@W_ih^T)
constexpr int W_GH   = W_GX + B * 3 * H;   // B*3H  (raw lh@W_hh^T, atomic-accumulated)
constexpr int W_HW   = W_GH + B * 3 * H;   // B*H  (h * w_h)
constexpr int W_HD   = W_HW + B * H;       // B*H  (h * w_d)
constexpr int W_SC   = W_HD + B * H;       // B*S  att_scores
constexpr int W_DEN  = W_SC + B * S;       // B*S  temporal denominator
constexpr int W_CMB  = W_DEN + B * S;      // B*TH1 combined
constexpr int W_LE   = W_CMB + B * TH1;    // B*E  logits_e
constexpr int W_RMAX = W_LE + B * E;       // B
constexpr int W_RSUM = W_RMAX + B;         // B
constexpr int W_PM   = W_RSUM + B;         // B*10 partial max
constexpr int W_PS   = W_PM + B * 10;      // B*10 partial sum

__device__ __forceinline__ float wave_sum(float v) {
#pragma unroll
  for (int o = 32; o > 0; o >>= 1) v += __shfl_xor(v, o);
  return v;
}

// ---------------- init: gather emb rows, zero gh accumulator + enc-ctx slice, set control
__global__ void k_init(const int* __restrict__ tok, const float* __restrict__ emb,
                       const float* __restrict__ ctrl, float* __restrict__ ws) {
  int i = blockIdx.x * 256 + threadIdx.x;   // 65536 threads
  if (i < B * E) {
    int b = i >> 7, e = i & 127;
    ws[W_X + i] = emb[tok[b] * E + e];
  }
  if (i < B * H) {
    int b = i >> 9, h = i & 511;
    ws[W_CMB + b * TH1 + H + h] = 0.f;   // encoder_context accumulator
  }
  if (i < B) ws[W_CMB + i * TH1 + 3 * H] = ctrl[i];
  // zero the gh split-K accumulator (B*3H = 196608 floats, 3 per thread)
#pragma unroll
  for (int j = 0; j < 3; ++j) ws[W_GH + i + j * 65536] = 0.f;
}

// ---------------- fused GRU GEMMs: W_GX = x@W_ih^T (direct), W_GH += lh@W_hh^T (split-K x4)
// grid (48, 5): x -> n-tile of 32 (N=1536); y==0 -> ih gemm (K=128);
// y in 1..4 -> hh gemm (K=512), k-range [(y-1)*128, y*128).
// block tile: 128b x 32n, BK=32, 4 subchunks per block.
__global__ __launch_bounds__(256) void k_grugemm(
    const float* __restrict__ x, const float* __restrict__ lh,
    const float* __restrict__ Wih, const float* __restrict__ Whh,
    float* __restrict__ ws) {
  __shared__ float As[32][132];   // [k][b], row 528B (16B-aligned)
  __shared__ float Ws[32][36];    // [k][n], row 144B (8B-aligned)
  const int tid = threadIdx.x;
  const int n0 = blockIdx.x * 32;
  const int y = blockIdx.y;
  const bool g0 = (y == 0);
  const float* A = g0 ? x : lh;
  const float* W = g0 ? Wih : Whh;
  const int K = g0 ? E : H;
  const int kbase = g0 ? 0 : (y - 1) * 128;
  const int tc = tid & 15;         // n pair: n = tc*2, tc*2+1
  const int tr = tid >> 4;         // b octet: b = tr*8 .. tr*8+7
  float acc[8][2] = {};
  for (int c = 0; c < 4; ++c) {
    const int k0 = kbase + c * 32;
    // stage A: 128 b x 32 k (4 float4 per thread, coalesced along k)
    {
      int i = tid;
#pragma unroll
      for (int it = 0; it < 4; ++it, i += 256) {
        int b = i >> 3, k4 = i & 7;
        float4 v = *(const float4*)&A[b * K + k0 + k4 * 4];
        As[k4 * 4 + 0][b] = v.x; As[k4 * 4 + 1][b] = v.y;
        As[k4 * 4 + 2][b] = v.z; As[k4 * 4 + 3][b] = v.w;
      }
    }
    // stage W: 32 n x 32 k (1 float4 per thread)
    {
      int n = tid >> 3, k4 = tid & 7;
      float4 v = *(const float4*)&W[(n0 + n) * K + k0 + k4 * 4];
      Ws[k4 * 4 + 0][n] = v.x; Ws[k4 * 4 + 1][n] = v.y;
      Ws[k4 * 4 + 2][n] = v.z; Ws[k4 * 4 + 3][n] = v.w;
    }
    __syncthreads();
#pragma unroll
    for (int kk = 0; kk < 32; ++kk) {
      float4 a0 = *(const float4*)&As[kk][tr * 8];
      float4 a1 = *(const float4*)&As[kk][tr * 8 + 4];
      float2 w = *(const float2*)&Ws[kk][tc * 2];
      float av[8] = {a0.x, a0.y, a0.z, a0.w, a1.x, a1.y, a1.z, a1.w};
#pragma unroll
      for (int i = 0; i < 8; ++i) {
        acc[i][0] += av[i] * w.x;
        acc[i][1] += av[i] * w.y;
      }
    }
    __syncthreads();
  }
  if (g0) {
#pragma unroll
    for (int i = 0; i < 8; ++i) {
      float* dst = ws + W_GX + (tr * 8 + i) * (3 * H) + n0 + tc * 2;
      dst[0] = acc[i][0]; dst[1] = acc[i][1];
    }
  } else {
#pragma unroll
    for (int i = 0; i < 8; ++i) {
      float* dst = ws + W_GH + (tr * 8 + i) * (3 * H) + n0 + tc * 2;
      atomicAdd(dst, acc[i][0]); atomicAdd(dst + 1, acc[i][1]);
    }
  }
}

// ---------------- GRU gates -> h, hw, hd, combined[:,0:H], out h slots (adds biases)
__global__ void k_gates(const float* __restrict__ ws_in, const float* __restrict__ lh,
                        const float* __restrict__ bih, const float* __restrict__ bhh,
                        const float* __restrict__ w_h, const float* __restrict__ w_d,
                        float* __restrict__ ws, float* __restrict__ out) {
  int i = blockIdx.x * 256 + threadIdx.x;  // b*H + u
  int b = i >> 9, u = i & 511;
  const float* gx = ws_in + W_GX + b * (3 * H);
  const float* gh = ws_in + W_GH + b * (3 * H);
  float gxr = gx[u] + bih[u], gxz = gx[H + u] + bih[H + u], gxn = gx[2 * H + u] + bih[2 * H + u];
  float ghr = gh[u] + bhh[u], ghz = gh[H + u] + bhh[H + u], ghn = gh[2 * H + u] + bhh[2 * H + u];
  float r = 1.f / (1.f + __expf(-(gxr + ghr)));
  float z = 1.f / (1.f + __expf(-(gxz + ghz)));
  float n = tanhf(gxn + r * ghn);
  float lhv = lh[i];
  float h = (1.f - z) * n + z * lhv;
  out[O_H + i] = h;
  out[O_DHS + b * ((T + 1) * H) + T * H + u] = h;
  ws[W_CMB + b * TH1 + u] = h;
  ws[W_HW + i] = h * w_h[u];
  ws[W_HD + i] = h * w_d[u];
}

// ---------------- temporal denominator + copy previous_att into new_previous_att
__global__ void k_den(const float* __restrict__ pa, float* __restrict__ ws,
                      float* __restrict__ out) {
  int i = blockIdx.x * 256 + threadIdx.x;
  if (i >= B * S) return;
  int b = i / S, s = i - b * S;
  float acc = 0.f;
  for (int t = 0; t < T; ++t) {
    float v = pa[(b * T + t) * S + s];
    out[O_NPA + (b * (T + 1) + t) * S + s] = v;
    acc += __expf(v);
  }
  ws[W_DEN + i] = acc;
}

// ---------------- attention scores vs encoder (wave per (b,s))
__global__ void k_escore(const float* __restrict__ enc, float* __restrict__ ws,
                         float* __restrict__ out) {
  int blk = blockIdx.x;             // b*25 + sgrp
  int b = blk / 25, sgrp = blk % 25;
  int wave = threadIdx.x >> 6, lane = threadIdx.x & 63;
  const float4* hw4 = (const float4*)(ws + W_HW + b * H);
  float4 h0 = hw4[lane * 2], h1 = hw4[lane * 2 + 1];
#pragma unroll
  for (int ii = 0; ii < 4; ++ii) {
    int s = sgrp * 16 + wave * 4 + ii;
    const float4* e4 = (const float4*)(enc + (b * S + s) * H);
    float4 e0 = e4[lane * 2], e1 = e4[lane * 2 + 1];
    float d = h0.x * e0.x + h0.y * e0.y + h0.z * e0.z + h0.w * e0.w +
              h1.x * e1.x + h1.y * e1.y + h1.z * e1.z + h1.w * e1.w;
    d = wave_sum(d);
    if (lane == 0) {
      ws[W_SC + b * S + s] = d;
      out[O_NPA + (b * (T + 1) + T) * S + s] = d;
    }
  }
}

// ---------------- att_dist (temporal softmax-ish), block per b
__global__ void k_attdist(const float* __restrict__ ws, float* __restrict__ out) {
  int b = blockIdx.x, tid = threadIdx.x;
  __shared__ float red[4];
  int s0 = tid, s1 = tid + 256;
  float t0 = __expf(ws[W_SC + b * S + s0]) / ws[W_DEN + b * S + s0];
  float t1 = 0.f;
  if (s1 < S) t1 = __expf(ws[W_SC + b * S + s1]) / ws[W_DEN + b * S + s1];
  float loc = wave_sum(t0 + t1);
  if ((tid & 63) == 0) red[tid >> 6] = loc;
  __syncthreads();
  float inv = 1.f / (red[0] + red[1] + red[2] + red[3]);
  out[O_ATT + b * S + s0] = t0 * inv;
  if (s1 < S) out[O_ATT + b * S + s1] = t1 * inv;
}

// ---------------- decoder attention: scores, softmax, context, copy prev rows
__global__ void k_dec(const float* __restrict__ pd, float* __restrict__ ws,
                      float* __restrict__ out) {
  int b = blockIdx.x, tid = threadIdx.x;
  int wave = tid >> 6, lane = tid & 63;
  __shared__ float sc[T];
  const float4* hd4 = (const float4*)(ws + W_HD + b * H);
  float4 d0 = hd4[lane * 2], d1 = hd4[lane * 2 + 1];
  for (int t = wave; t < T; t += 4) {
    const float4* p4 = (const float4*)(pd + (b * T + t) * H);
    float4 p0 = p4[lane * 2], p1 = p4[lane * 2 + 1];
    float v = d0.x * p0.x + d0.y * p0.y + d0.z * p0.z + d0.w * p0.w +
              d1.x * p1.x + d1.y * p1.y + d1.z * p1.z + d1.w * p1.w;
    v = wave_sum(v);
    if (lane == 0) sc[t] = v;
  }
  __syncthreads();
  if (tid < 64) {
    float v = (lane < T) ? sc[lane] : -1e30f;
    float m = v;
#pragma unroll
    for (int o = 32; o > 0; o >>= 1) m = fmaxf(m, __shfl_xor(m, o));
    float e = (lane < T) ? __expf(v - m) : 0.f;
    float ssum = wave_sum(e);
    if (lane < T) sc[lane] = e / ssum;
  }
  __syncthreads();
  float a0 = 0.f, a1 = 0.f;
  int h0 = tid, h1 = tid + 256;
  for (int t = 0; t < T; ++t) {
    float wt = sc[t];
    a0 += wt * pd[(b * T + t) * H + h0];
    a1 += wt * pd[(b * T + t) * H + h1];
  }
  ws[W_CMB + b * TH1 + 2 * H + h0] = a0;
  ws[W_CMB + b * TH1 + 2 * H + h1] = a1;
  // copy prev decoder states into output rows [0..T)
  const float4* src = (const float4*)(pd + b * T * H);
  float4* dst = (float4*)(out + O_DHS + b * (T + 1) * H);
  for (int i = tid; i < T * H / 4; i += 256) dst[i] = src[i];
}

// ---------------- encoder context: (b, s-chunk) partial + atomic accumulate
__global__ void k_encctx(const float* __restrict__ enc, const float* __restrict__ out,
                         float* __restrict__ ws) {
  int blk = blockIdx.x;
  int b = blk / 5, c = blk % 5;
  int s0 = c * 80, tid = threadIdx.x;
  __shared__ float ad[80];
  if (tid < 80) ad[tid] = out[O_ATT + b * S + s0 + tid];
  __syncthreads();
  float a0 = 0.f, a1 = 0.f;
  int h0 = tid, h1 = tid + 256;
  for (int j = 0; j < 80; ++j) {
    float w = ad[j];
    const float* ep = enc + (b * S + s0 + j) * H;
    a0 += w * ep[h0];
    a1 += w * ep[h1];
  }
  atomicAdd(&ws[W_CMB + b * TH1 + H + h0], a0);
  atomicAdd(&ws[W_CMB + b * TH1 + H + h1], a1);
}

// ---------------- logits_e = combined @ outh_W^T + outh_b
// wave-per-e, 8 b-rows staged in LDS, outh_W row held in registers.
__global__ __launch_bounds__(256) void k_outh2(const float* __restrict__ oW,
                                               const float* __restrict__ ob,
                                               float* __restrict__ ws) {
  __shared__ float cmb[8 * TH1];
  const int tid = threadIdx.x;
  const int b0 = blockIdx.y * 8;
  const int e = blockIdx.x * 4 + (tid >> 6);
  const int lane = tid & 63;
  const float* src = ws + W_CMB + b0 * TH1;
  for (int i = tid; i < 8 * TH1; i += 256) cmb[i] = src[i];
  float wr[25];
  const float* wrow = oW + e * TH1;
#pragma unroll
  for (int j = 0; j < 25; ++j) {
    int k = lane + 64 * j;
    wr[j] = (k < TH1) ? wrow[k] : 0.f;
  }
  __syncthreads();
  float bias = ob[e];
#pragma unroll 1
  for (int bb = 0; bb < 8; ++bb) {
    const float* c = cmb + bb * TH1;
    float a = 0.f;
#pragma unroll
    for (int j = 0; j < 25; ++j) {
      int k = lane + 64 * j;
      float cv = (k < TH1) ? c[k] : 0.f;
      a += wr[j] * cv;
    }
    a = wave_sum(a);
    if (lane == 0) ws[W_LE + (b0 + bb) * E + e] = a + bias;
  }
}

// ---------------- p_gen (one wave per b)
__global__ void k_gen(const float* __restrict__ gW, const float* __restrict__ gb,
                      const float* __restrict__ ws, float* __restrict__ out) {
  int b = blockIdx.x, lane = threadIdx.x;
  float acc = 0.f;
  for (int k = lane; k < TH1; k += 64) acc += gW[k] * ws[W_CMB + b * TH1 + k];
  acc = wave_sum(acc);
  if (lane == 0) out[O_PGEN + b] = 1.f / (1.f + __expf(-(acc + gb[0])));
}

// ---------------- generic tiled f32 GEMM: C[M][N] = A[M][K] * B[N][K]^T + bias[N]
template <int BM, int BN, int BK, int TM, int TN>
__global__ __launch_bounds__(256) void gemm_abt(
    const float* __restrict__ A, const float* __restrict__ Bm,
    const float* __restrict__ bias, float* __restrict__ C, int M, int N, int K) {
  __shared__ float As[BK][BM + 4];
  __shared__ float Bs[BK][BN + 4];
  const int tid = threadIdx.x;
  const int m0 = blockIdx.y * BM, n0 = blockIdx.x * BN;
  constexpr int TC = BN / TN;
  const int tr = tid / TC, tc = tid % TC;
  float acc[TM][TN] = {};
  for (int k0 = 0; k0 < K; k0 += BK) {
    for (int i = tid; i < BM * BK; i += 256) {
      int m = i / BK, k = i % BK;
      float v = 0.f;
      if (m0 + m < M && k0 + k < K) v = A[(m0 + m) * K + k0 + k];
      As[k][m] = v;
    }
    for (int i = tid; i < BN * BK; i += 256) {
      int n = i / BK, k = i % BK;
      float v = 0.f;
      if (n0 + n < N && k0 + k < K) v = Bm[(n0 + n) * K + k0 + k];
      Bs[k][n] = v;
    }
    __syncthreads();
#pragma unroll
    for (int k = 0; k < BK; ++k) {
      float a[TM], bb[TN];
#pragma unroll
      for (int i = 0; i < TM; ++i) a[i] = As[k][tr * TM + i];
#pragma unroll
      for (int j = 0; j < TN; ++j) bb[j] = Bs[k][tc * TN + j];
#pragma unroll
      for (int i = 0; i < TM; ++i)
#pragma unroll
        for (int j = 0; j < TN; ++j) acc[i][j] += a[i] * bb[j];
    }
    __syncthreads();
  }
#pragma unroll
  for (int i = 0; i < TM; ++i) {
    int m = m0 + tr * TM + i;
    if (m >= M) continue;
#pragma unroll
    for (int j = 0; j < TN; ++j) {
      int n = n0 + tc * TN + j;
      if (n < N) C[m * N + n] = acc[i][j] + bias[n];
    }
  }
}

// ---------------- vocab softmax pass 1a: partial max/sum per (b, chunk)
__global__ void k_rowstat1(const float* __restrict__ out, float* __restrict__ ws) {
  int c = blockIdx.x, b = blockIdx.y, tid = threadIdx.x;
  const float4* l4 = (const float4*)(out + O_PVOCAB + b * V);
  int base = c * 1250;
  float m = -1e30f, ssum = 0.f;
  for (int i = base + tid; i < base + 1250; i += 256) {
    float4 v = l4[i];
    float mm = fmaxf(fmaxf(v.x, v.y), fmaxf(v.z, v.w));
    if (mm > m) { ssum *= __expf(m - mm); m = mm; }
    ssum += __expf(v.x - m) + __expf(v.y - m) + __expf(v.z - m) + __expf(v.w - m);
  }
  __shared__ float mred[4], sred[4];
#pragma unroll
  for (int o = 32; o > 0; o >>= 1) {
    float om = __shfl_xor(m, o), os = __shfl_xor(ssum, o);
    float nm = fmaxf(m, om);
    ssum = ssum * __expf(m - nm) + os * __expf(om - nm);
    m = nm;
  }
  if ((tid & 63) == 0) { mred[tid >> 6] = m; sred[tid >> 6] = ssum; }
  __syncthreads();
  if (tid == 0) {
    float M = mred[0], SS = sred[0];
    for (int w = 1; w < 4; ++w) {
      float nm = fmaxf(M, mred[w]);
      SS = SS * __expf(M - nm) + sred[w] * __expf(mred[w] - nm);
      M = nm;
    }
    ws[W_PM + b * 10 + c] = M;
    ws[W_PS + b * 10 + c] = SS;
  }
}

// ---------------- vocab softmax pass 1b: combine 10 partials per b
__global__ void k_rowstat2(float* __restrict__ ws) {
  int b = threadIdx.x;  // 128 threads
  float M = -1e30f;
#pragma unroll
  for (int c = 0; c < 10; ++c) M = fmaxf(M, ws[W_PM + b * 10 + c]);
  float SS = 0.f;
#pragma unroll
  for (int c = 0; c < 10; ++c) SS += ws[W_PS + b * 10 + c] * __expf(ws[W_PM + b * 10 + c] - M);
  ws[W_RMAX + b] = M;
  ws[W_RSUM + b] = SS;
}

// ---------------- vocab softmax pass 2: p_vocab (in place) + p_final main region
__global__ void k_pvocab(const float* __restrict__ ws, float* __restrict__ out) {
  int b = blockIdx.y;
  int i = blockIdx.x * 256 + threadIdx.x;
  if (i >= V / 4) return;
  float m = ws[W_RMAX + b], inv = 1.f / ws[W_RSUM + b];
  float pg = out[O_PGEN + b];
  float4 v = ((const float4*)(out + O_PVOCAB + b * V))[i];
  float4 p;
  p.x = __expf(v.x - m) * inv;
  p.y = __expf(v.y - m) * inv;
  p.z = __expf(v.z - m) * inv;
  p.w = __expf(v.w - m) * inv;
  ((float4*)(out + O_PVOCAB + b * V))[i] = p;
  float4 pf;
  pf.x = pg * p.x; pf.y = pg * p.y; pf.z = pg * p.z; pf.w = pg * p.w;
  ((float4*)(out + O_PFINAL + b * NV))[i] = pf;
}

// ---------------- zero pad region of p_final
__global__ void k_pad(float* __restrict__ out) {
  int i = blockIdx.x * 256 + threadIdx.x;
  if (i >= B * PADV / 4) return;
  int b = i / (PADV / 4), j = i % (PADV / 4);
  ((float4*)(out + O_PFINAL + b * NV + V))[j] = make_float4(0.f, 0.f, 0.f, 0.f);
}

// ---------------- scatter (1-p_gen)*att_dist into p_final
__global__ void k_scatter(const int* __restrict__ fiv, float* __restrict__ out) {
  int i = blockIdx.x * 256 + threadIdx.x;
  if (i >= B * S) return;
  int b = i / S;
  int idx = fiv[i];
  float pg = out[O_PGEN + b];
  float val = (1.f - pg) * out[O_ATT + i];
  atomicAdd(out + O_PFINAL + b * NV + idx, val);
}

extern "C" void kernel_launch(void* const* d_in, const int* in_sizes, int n_in,
                              void* d_out, int out_size, void* d_ws, size_t ws_size,
                              hipStream_t stream) {
  const int*   tok  = (const int*)d_in[0];
  const float* pd   = (const float*)d_in[1];
  const float* lh   = (const float*)d_in[2];
  const float* enc  = (const float*)d_in[3];
  const int*   fiv  = (const int*)d_in[4];
  const float* pa   = (const float*)d_in[5];
  const float* ctrl = (const float*)d_in[6];
  const float* emb  = (const float*)d_in[7];
  const float* W_ih = (const float*)d_in[8];
  const float* W_hh = (const float*)d_in[9];
  const float* b_ih = (const float*)d_in[10];
  const float* b_hh = (const float*)d_in[11];
  const float* w_h  = (const float*)d_in[12];
  const float* w_d  = (const float*)d_in[13];
  const float* gW   = (const float*)d_in[14];
  const float* gb   = (const float*)d_in[15];
  const float* ohW  = (const float*)d_in[16];
  const float* ohb  = (const float*)d_in[17];
  const float* ovW  = (const float*)d_in[18];
  const float* ovb  = (const float*)d_in[19];
  float* out = (float*)d_out;
  float* ws  = (float*)d_ws;

  k_init<<<256, 256, 0, stream>>>(tok, emb, ctrl, ws);
  k_grugemm<<<dim3(48, 5), 256, 0, stream>>>(ws + W_X, lh, W_ih, W_hh, ws);
  k_gates<<<256, 256, 0, stream>>>(ws, lh, b_ih, b_hh, w_h, w_d, ws, out);
  k_den<<<200, 256, 0, stream>>>(pa, ws, out);
  k_escore<<<3200, 256, 0, stream>>>(enc, ws, out);
  k_attdist<<<128, 256, 0, stream>>>(ws, out);
  k_dec<<<128, 256, 0, stream>>>(pd, ws, out);
  k_encctx<<<640, 256, 0, stream>>>(enc, out, ws);
  k_outh2<<<dim3(32, 16), 256, 0, stream>>>(ohW, ohb, ws);
  k_gen<<<128, 64, 0, stream>>>(gW, gb, ws, out);
  gemm_abt<128, 64, 32, 8, 4><<<dim3((V + 63) / 64, 1), 256, 0, stream>>>(ws + W_LE, ovW, ovb, out + O_PVOCAB, B, V, E);
  k_rowstat1<<<dim3(10, 128), 256, 0, stream>>>(out, ws);
  k_rowstat2<<<1, 128, 0, stream>>>(ws);
  k_pvocab<<<dim3(49, 128), 256, 0, stream>>>(ws, out);
  k_pad<<<125, 256, 0, stream>>>(out);
  k_scatter<<<200, 256, 0, stream>>>(fiv, out);
}

// Round 5
// 386.681 us; speedup vs baseline: 1.8885x; 1.0751x over previous
//
#include <hip/hip_runtime.h>
#include <hip/hip_bf16.h>
#include <math.h>

// Problem constants
constexpr int B = 128, S = 400, T = 50, H = 512, E = 128, V = 50000, PADV = 1000;
constexpr int NV = V + PADV;        // 51000
constexpr int TH1 = 3 * H + 1;      // 1537
constexpr int NBLK = 391;           // vocab gemm blocks (ceil(50000/128))

// Output offsets (floats), in reference return order
constexpr int O_PFINAL = 0;                      // B*NV
constexpr int O_PGEN   = O_PFINAL + B * NV;      // B
constexpr int O_PVOCAB = O_PGEN + B;             // B*V
constexpr int O_ATT    = O_PVOCAB + B * V;       // B*S
constexpr int O_DHS    = O_ATT + B * S;          // B*(T+1)*H
constexpr int O_H      = O_DHS + B * (T + 1) * H;// B*H
constexpr int O_NPA    = O_H + B * H;            // B*(T+1)*S

// Workspace offsets (floats)
constexpr int W_X    = 0;                  // B*E gathered embedding
constexpr int W_GX   = W_X + B * E;        // B*3H  (raw x@W_ih^T)
constexpr int W_GH   = W_GX + B * 3 * H;   // B*3H  (raw lh@W_hh^T, atomic-accumulated)
constexpr int W_HW   = W_GH + B * 3 * H;   // B*H  (h * w_h)
constexpr int W_HD   = W_HW + B * H;       // B*H  (h * w_d)
constexpr int W_SC   = W_HD + B * H;       // B*S  att_scores
constexpr int W_DEN  = W_SC + B * S;       // B*S  temporal denominator
constexpr int W_CMB  = W_DEN + B * S;      // B*TH1 combined
constexpr int W_LE   = W_CMB + B * TH1;    // B*E  logits_e
constexpr int W_RMAX = W_LE + B * E;       // B
constexpr int W_RSUM = W_RMAX + B;         // B
constexpr int W_PM   = W_RSUM + B;         // B*NBLK partial max
constexpr int W_PS   = W_PM + B * NBLK;    // B*NBLK partial sumexp

__device__ __forceinline__ float wave_sum(float v) {
#pragma unroll
  for (int o = 32; o > 0; o >>= 1) v += __shfl_xor(v, o);
  return v;
}

// ---------------- init: gather emb rows, zero gh accumulator + enc-ctx slice, set control
__global__ void k_init(const int* __restrict__ tok, const float* __restrict__ emb,
                       const float* __restrict__ ctrl, float* __restrict__ ws) {
  int i = blockIdx.x * 256 + threadIdx.x;   // 65536 threads
  if (i < B * E) {
    int b = i >> 7, e = i & 127;
    ws[W_X + i] = emb[tok[b] * E + e];
  }
  if (i < B * H) {
    int b = i >> 9, h = i & 511;
    ws[W_CMB + b * TH1 + H + h] = 0.f;   // encoder_context accumulator
  }
  if (i < B) ws[W_CMB + i * TH1 + 3 * H] = ctrl[i];
  // zero the gh split-K accumulator (B*3H = 196608 floats, 3 per thread)
#pragma unroll
  for (int j = 0; j < 3; ++j) ws[W_GH + i + j * 65536] = 0.f;
}

// ---------------- fused GRU GEMMs: W_GX = x@W_ih^T (direct), W_GH += lh@W_hh^T (split-K x4)
__global__ __launch_bounds__(256) void k_grugemm(
    const float* __restrict__ x, const float* __restrict__ lh,
    const float* __restrict__ Wih, const float* __restrict__ Whh,
    float* __restrict__ ws) {
  __shared__ float As[32][132];
  __shared__ float Ws[32][36];
  const int tid = threadIdx.x;
  const int n0 = blockIdx.x * 32;
  const int y = blockIdx.y;
  const bool g0 = (y == 0);
  const float* A = g0 ? x : lh;
  const float* W = g0 ? Wih : Whh;
  const int K = g0 ? E : H;
  const int kbase = g0 ? 0 : (y - 1) * 128;
  const int tc = tid & 15;
  const int tr = tid >> 4;
  float acc[8][2] = {};
  for (int c = 0; c < 4; ++c) {
    const int k0 = kbase + c * 32;
    {
      int i = tid;
#pragma unroll
      for (int it = 0; it < 4; ++it, i += 256) {
        int b = i >> 3, k4 = i & 7;
        float4 v = *(const float4*)&A[b * K + k0 + k4 * 4];
        As[k4 * 4 + 0][b] = v.x; As[k4 * 4 + 1][b] = v.y;
        As[k4 * 4 + 2][b] = v.z; As[k4 * 4 + 3][b] = v.w;
      }
    }
    {
      int n = tid >> 3, k4 = tid & 7;
      float4 v = *(const float4*)&W[(n0 + n) * K + k0 + k4 * 4];
      Ws[k4 * 4 + 0][n] = v.x; Ws[k4 * 4 + 1][n] = v.y;
      Ws[k4 * 4 + 2][n] = v.z; Ws[k4 * 4 + 3][n] = v.w;
    }
    __syncthreads();
#pragma unroll
    for (int kk = 0; kk < 32; ++kk) {
      float4 a0 = *(const float4*)&As[kk][tr * 8];
      float4 a1 = *(const float4*)&As[kk][tr * 8 + 4];
      float2 w = *(const float2*)&Ws[kk][tc * 2];
      float av[8] = {a0.x, a0.y, a0.z, a0.w, a1.x, a1.y, a1.z, a1.w};
#pragma unroll
      for (int i = 0; i < 8; ++i) {
        acc[i][0] += av[i] * w.x;
        acc[i][1] += av[i] * w.y;
      }
    }
    __syncthreads();
  }
  if (g0) {
#pragma unroll
    for (int i = 0; i < 8; ++i) {
      float* dst = ws + W_GX + (tr * 8 + i) * (3 * H) + n0 + tc * 2;
      dst[0] = acc[i][0]; dst[1] = acc[i][1];
    }
  } else {
#pragma unroll
    for (int i = 0; i < 8; ++i) {
      float* dst = ws + W_GH + (tr * 8 + i) * (3 * H) + n0 + tc * 2;
      atomicAdd(dst, acc[i][0]); atomicAdd(dst + 1, acc[i][1]);
    }
  }
}

// ---------------- GRU gates -> h, hw, hd, combined[:,0:H], out h slots (adds biases)
__global__ void k_gates(const float* __restrict__ ws_in, const float* __restrict__ lh,
                        const float* __restrict__ bih, const float* __restrict__ bhh,
                        const float* __restrict__ w_h, const float* __restrict__ w_d,
                        float* __restrict__ ws, float* __restrict__ out) {
  int i = blockIdx.x * 256 + threadIdx.x;  // b*H + u
  int b = i >> 9, u = i & 511;
  const float* gx = ws_in + W_GX + b * (3 * H);
  const float* gh = ws_in + W_GH + b * (3 * H);
  float gxr = gx[u] + bih[u], gxz = gx[H + u] + bih[H + u], gxn = gx[2 * H + u] + bih[2 * H + u];
  float ghr = gh[u] + bhh[u], ghz = gh[H + u] + bhh[H + u], ghn = gh[2 * H + u] + bhh[2 * H + u];
  float r = 1.f / (1.f + __expf(-(gxr + ghr)));
  float z = 1.f / (1.f + __expf(-(gxz + ghz)));
  float n = tanhf(gxn + r * ghn);
  float lhv = lh[i];
  float h = (1.f - z) * n + z * lhv;
  out[O_H + i] = h;
  out[O_DHS + b * ((T + 1) * H) + T * H + u] = h;
  ws[W_CMB + b * TH1 + u] = h;
  ws[W_HW + i] = h * w_h[u];
  ws[W_HD + i] = h * w_d[u];
}

// ---------------- temporal denominator + copy previous_att into new_previous_att
__global__ void k_den(const float* __restrict__ pa, float* __restrict__ ws,
                      float* __restrict__ out) {
  int i = blockIdx.x * 256 + threadIdx.x;
  if (i >= B * S) return;
  int b = i / S, s = i - b * S;
  float acc = 0.f;
  for (int t = 0; t < T; ++t) {
    float v = pa[(b * T + t) * S + s];
    out[O_NPA + (b * (T + 1) + t) * S + s] = v;
    acc += __expf(v);
  }
  ws[W_DEN + i] = acc;
}

// ---------------- attention scores vs encoder (wave per (b,s))
__global__ void k_escore(const float* __restrict__ enc, float* __restrict__ ws,
                         float* __restrict__ out) {
  int blk = blockIdx.x;             // b*25 + sgrp
  int b = blk / 25, sgrp = blk % 25;
  int wave = threadIdx.x >> 6, lane = threadIdx.x & 63;
  const float4* hw4 = (const float4*)(ws + W_HW + b * H);
  float4 h0 = hw4[lane * 2], h1 = hw4[lane * 2 + 1];
#pragma unroll
  for (int ii = 0; ii < 4; ++ii) {
    int s = sgrp * 16 + wave * 4 + ii;
    const float4* e4 = (const float4*)(enc + (b * S + s) * H);
    float4 e0 = e4[lane * 2], e1 = e4[lane * 2 + 1];
    float d = h0.x * e0.x + h0.y * e0.y + h0.z * e0.z + h0.w * e0.w +
              h1.x * e1.x + h1.y * e1.y + h1.z * e1.z + h1.w * e1.w;
    d = wave_sum(d);
    if (lane == 0) {
      ws[W_SC + b * S + s] = d;
      out[O_NPA + (b * (T + 1) + T) * S + s] = d;
    }
  }
}

// ---------------- att_dist (temporal softmax-ish), block per b
__global__ void k_attdist(const float* __restrict__ ws, float* __restrict__ out) {
  int b = blockIdx.x, tid = threadIdx.x;
  __shared__ float red[4];
  int s0 = tid, s1 = tid + 256;
  float t0 = __expf(ws[W_SC + b * S + s0]) / ws[W_DEN + b * S + s0];
  float t1 = 0.f;
  if (s1 < S) t1 = __expf(ws[W_SC + b * S + s1]) / ws[W_DEN + b * S + s1];
  float loc = wave_sum(t0 + t1);
  if ((tid & 63) == 0) red[tid >> 6] = loc;
  __syncthreads();
  float inv = 1.f / (red[0] + red[1] + red[2] + red[3]);
  out[O_ATT + b * S + s0] = t0 * inv;
  if (s1 < S) out[O_ATT + b * S + s1] = t1 * inv;
}

// ---------------- decoder attention: scores, softmax, context (copy moved out)
__global__ void k_dec(const float* __restrict__ pd, float* __restrict__ ws,
                      float* __restrict__ out) {
  int b = blockIdx.x, tid = threadIdx.x;
  int wave = tid >> 6, lane = tid & 63;
  __shared__ float sc[T];
  const float4* hd4 = (const float4*)(ws + W_HD + b * H);
  float4 d0 = hd4[lane * 2], d1 = hd4[lane * 2 + 1];
  for (int t = wave; t < T; t += 4) {
    const float4* p4 = (const float4*)(pd + (b * T + t) * H);
    float4 p0 = p4[lane * 2], p1 = p4[lane * 2 + 1];
    float v = d0.x * p0.x + d0.y * p0.y + d0.z * p0.z + d0.w * p0.w +
              d1.x * p1.x + d1.y * p1.y + d1.z * p1.z + d1.w * p1.w;
    v = wave_sum(v);
    if (lane == 0) sc[t] = v;
  }
  __syncthreads();
  if (tid < 64) {
    float v = (lane < T) ? sc[lane] : -1e30f;
    float m = v;
#pragma unroll
    for (int o = 32; o > 0; o >>= 1) m = fmaxf(m, __shfl_xor(m, o));
    float e = (lane < T) ? __expf(v - m) : 0.f;
    float ssum = wave_sum(e);
    if (lane < T) sc[lane] = e / ssum;
  }
  __syncthreads();
  float a0 = 0.f, a1 = 0.f;
  int h0 = tid, h1 = tid + 256;
  for (int t = 0; t < T; ++t) {
    float wt = sc[t];
    a0 += wt * pd[(b * T + t) * H + h0];
    a1 += wt * pd[(b * T + t) * H + h1];
  }
  ws[W_CMB + b * TH1 + 2 * H + h0] = a0;
  ws[W_CMB + b * TH1 + 2 * H + h1] = a1;
}

// ---------------- flat copy of prev decoder states into decoder_h_states rows [0..T)
__global__ void k_dhscopy(const float* __restrict__ pd, float* __restrict__ out) {
  int i = blockIdx.x * 256 + threadIdx.x;      // float4 index over B*T*H/4
  if (i >= B * T * H / 4) return;
  int b = i / (T * H / 4), rem = i - b * (T * H / 4);
  ((float4*)(out + O_DHS + b * (T + 1) * H))[rem] = ((const float4*)(pd + b * T * H))[rem];
}

// ---------------- encoder context: (b, s-chunk) partial + atomic accumulate
__global__ void k_encctx(const float* __restrict__ enc, const float* __restrict__ out,
                         float* __restrict__ ws) {
  int blk = blockIdx.x;
  int b = blk / 5, c = blk % 5;
  int s0 = c * 80, tid = threadIdx.x;
  __shared__ float ad[80];
  if (tid < 80) ad[tid] = out[O_ATT + b * S + s0 + tid];
  __syncthreads();
  float a0 = 0.f, a1 = 0.f;
  int h0 = tid, h1 = tid + 256;
  for (int j = 0; j < 80; ++j) {
    float w = ad[j];
    const float* ep = enc + (b * S + s0 + j) * H;
    a0 += w * ep[h0];
    a1 += w * ep[h1];
  }
  atomicAdd(&ws[W_CMB + b * TH1 + H + h0], a0);
  atomicAdd(&ws[W_CMB + b * TH1 + H + h1], a1);
}

// ---------------- logits_e = combined @ outh_W^T + outh_b
__global__ __launch_bounds__(256) void k_outh2(const float* __restrict__ oW,
                                               const float* __restrict__ ob,
                                               float* __restrict__ ws) {
  __shared__ float cmb[8 * TH1];
  const int tid = threadIdx.x;
  const int b0 = blockIdx.y * 8;
  const int e = blockIdx.x * 4 + (tid >> 6);
  const int lane = tid & 63;
  const float* src = ws + W_CMB + b0 * TH1;
  for (int i = tid; i < 8 * TH1; i += 256) cmb[i] = src[i];
  float wr[25];
  const float* wrow = oW + e * TH1;
#pragma unroll
  for (int j = 0; j < 25; ++j) {
    int k = lane + 64 * j;
    wr[j] = (k < TH1) ? wrow[k] : 0.f;
  }
  __syncthreads();
  float bias = ob[e];
#pragma unroll 1
  for (int bb = 0; bb < 8; ++bb) {
    const float* c = cmb + bb * TH1;
    float a = 0.f;
#pragma unroll
    for (int j = 0; j < 25; ++j) {
      int k = lane + 64 * j;
      float cv = (k < TH1) ? c[k] : 0.f;
      a += wr[j] * cv;
    }
    a = wave_sum(a);
    if (lane == 0) ws[W_LE + (b0 + bb) * E + e] = a + bias;
  }
}

// ---------------- p_gen (one wave per b)
__global__ void k_gen(const float* __restrict__ gW, const float* __restrict__ gb,
                      const float* __restrict__ ws, float* __restrict__ out) {
  int b = blockIdx.x, lane = threadIdx.x;
  float acc = 0.f;
  for (int k = lane; k < TH1; k += 64) acc += gW[k] * ws[W_CMB + b * TH1 + k];
  acc = wave_sum(acc);
  if (lane == 0) out[O_PGEN + b] = 1.f / (1.f + __expf(-(acc + gb[0])));
}

// ---------------- vocab GEMM: C[128][V] = A[128][128] @ W[V][128]^T + bias
// 8x8 register tile, BM=128(all), BN=128, fused per-block row max/sumexp partials.
__global__ __launch_bounds__(256) void k_vgemm(
    const float* __restrict__ A, const float* __restrict__ W,
    const float* __restrict__ bias, float* __restrict__ C,
    float* __restrict__ ws) {
  __shared__ float As[32][132];
  __shared__ float Bs[32][132];
  const int tid = threadIdx.x;
  const int n0 = blockIdx.x * 128;
  const int tr = tid >> 4;        // rows tr*8..+7
  const int tc = tid & 15;        // cols tc*8..+7
  float acc[8][8] = {};
#pragma unroll 1
  for (int c = 0; c < 4; ++c) {
    const int k0 = c * 32;
    // stage A chunk: 128 rows x 32 k
    {
      int i = tid;
#pragma unroll
      for (int it = 0; it < 4; ++it, i += 256) {
        int m = i >> 3, k4 = i & 7;
        float4 v = *(const float4*)&A[m * 128 + k0 + k4 * 4];
        As[k4 * 4 + 0][m] = v.x; As[k4 * 4 + 1][m] = v.y;
        As[k4 * 4 + 2][m] = v.z; As[k4 * 4 + 3][m] = v.w;
      }
    }
    // stage W chunk: 128 cols x 32 k (bounds-guarded on last block)
    {
      int i = tid;
#pragma unroll
      for (int it = 0; it < 4; ++it, i += 256) {
        int n = i >> 3, k4 = i & 7;
        float4 v = make_float4(0.f, 0.f, 0.f, 0.f);
        if (n0 + n < V) v = *(const float4*)&W[(n0 + n) * 128 + k0 + k4 * 4];
        Bs[k4 * 4 + 0][n] = v.x; Bs[k4 * 4 + 1][n] = v.y;
        Bs[k4 * 4 + 2][n] = v.z; Bs[k4 * 4 + 3][n] = v.w;
      }
    }
    __syncthreads();
#pragma unroll 4
    for (int kk = 0; kk < 32; ++kk) {
      float4 a0 = *(const float4*)&As[kk][tr * 8];
      float4 a1 = *(const float4*)&As[kk][tr * 8 + 4];
      float4 b0 = *(const float4*)&Bs[kk][tc * 8];
      float4 b1 = *(const float4*)&Bs[kk][tc * 8 + 4];
      float av[8] = {a0.x, a0.y, a0.z, a0.w, a1.x, a1.y, a1.z, a1.w};
      float bw[8] = {b0.x, b0.y, b0.z, b0.w, b1.x, b1.y, b1.z, b1.w};
#pragma unroll
      for (int i = 0; i < 8; ++i)
#pragma unroll
        for (int j = 0; j < 8; ++j) acc[i][j] += av[i] * bw[j];
    }
    __syncthreads();
  }
  // epilogue: bias, stores, per-row partial max/sumexp over this block's 128 cols
  const int cbase = n0 + tc * 8;
  float bv[8];
#pragma unroll
  for (int j = 0; j < 8; ++j) bv[j] = (cbase + j < V) ? bias[cbase + j] : 0.f;
#pragma unroll
  for (int i = 0; i < 8; ++i) {
    int r = tr * 8 + i;
    float m = -1e30f;
#pragma unroll
    for (int j = 0; j < 8; ++j) {
      acc[i][j] += bv[j];
      if (cbase + j < V) m = fmaxf(m, acc[i][j]);
    }
#pragma unroll
    for (int o = 1; o < 16; o <<= 1) m = fmaxf(m, __shfl_xor(m, o));
    float s = 0.f;
#pragma unroll
    for (int j = 0; j < 8; ++j)
      if (cbase + j < V) s += __expf(acc[i][j] - m);
#pragma unroll
    for (int o = 1; o < 16; o <<= 1) s += __shfl_xor(s, o);
    if (tc == 0) {
      ws[W_PM + r * NBLK + blockIdx.x] = m;
      ws[W_PS + r * NBLK + blockIdx.x] = s;
    }
    if (cbase + 8 <= V) {
      *(float4*)&C[r * V + cbase] = make_float4(acc[i][0], acc[i][1], acc[i][2], acc[i][3]);
      *(float4*)&C[r * V + cbase + 4] = make_float4(acc[i][4], acc[i][5], acc[i][6], acc[i][7]);
    } else {
#pragma unroll
      for (int j = 0; j < 8; ++j)
        if (cbase + j < V) C[r * V + cbase + j] = acc[i][j];
    }
  }
}

// ---------------- combine NBLK partials per row (block per b)
__global__ void k_rowstat2(float* __restrict__ ws) {
  int b = blockIdx.x, tid = threadIdx.x;
  const float* pm = ws + W_PM + b * NBLK;
  const float* psv = ws + W_PS + b * NBLK;
  __shared__ float red[4];
  float m = -1e30f;
  for (int c = tid; c < NBLK; c += 256) m = fmaxf(m, pm[c]);
#pragma unroll
  for (int o = 32; o > 0; o >>= 1) m = fmaxf(m, __shfl_xor(m, o));
  if ((tid & 63) == 0) red[tid >> 6] = m;
  __syncthreads();
  float M = fmaxf(fmaxf(red[0], red[1]), fmaxf(red[2], red[3]));
  __syncthreads();
  float s = 0.f;
  for (int c = tid; c < NBLK; c += 256) s += psv[c] * __expf(pm[c] - M);
  s = wave_sum(s);
  if ((tid & 63) == 0) red[tid >> 6] = s;
  __syncthreads();
  if (tid == 0) {
    ws[W_RMAX + b] = M;
    ws[W_RSUM + b] = red[0] + red[1] + red[2] + red[3];
  }
}

// ---------------- vocab softmax pass 2: p_vocab (in place) + p_final main region
__global__ void k_pvocab(const float* __restrict__ ws, float* __restrict__ out) {
  int b = blockIdx.y;
  int i = blockIdx.x * 256 + threadIdx.x;
  if (i >= V / 4) return;
  float m = ws[W_RMAX + b], inv = 1.f / ws[W_RSUM + b];
  float pg = out[O_PGEN + b];
  float4 v = ((const float4*)(out + O_PVOCAB + b * V))[i];
  float4 p;
  p.x = __expf(v.x - m) * inv;
  p.y = __expf(v.y - m) * inv;
  p.z = __expf(v.z - m) * inv;
  p.w = __expf(v.w - m) * inv;
  ((float4*)(out + O_PVOCAB + b * V))[i] = p;
  float4 pf;
  pf.x = pg * p.x; pf.y = pg * p.y; pf.z = pg * p.z; pf.w = pg * p.w;
  ((float4*)(out + O_PFINAL + b * NV))[i] = pf;
}

// ---------------- zero pad region of p_final
__global__ void k_pad(float* __restrict__ out) {
  int i = blockIdx.x * 256 + threadIdx.x;
  if (i >= B * PADV / 4) return;
  int b = i / (PADV / 4), j = i % (PADV / 4);
  ((float4*)(out + O_PFINAL + b * NV + V))[j] = make_float4(0.f, 0.f, 0.f, 0.f);
}

// ---------------- scatter (1-p_gen)*att_dist into p_final
__global__ void k_scatter(const int* __restrict__ fiv, float* __restrict__ out) {
  int i = blockIdx.x * 256 + threadIdx.x;
  if (i >= B * S) return;
  int b = i / S;
  int idx = fiv[i];
  float pg = out[O_PGEN + b];
  float val = (1.f - pg) * out[O_ATT + i];
  atomicAdd(out + O_PFINAL + b * NV + idx, val);
}

extern "C" void kernel_launch(void* const* d_in, const int* in_sizes, int n_in,
                              void* d_out, int out_size, void* d_ws, size_t ws_size,
                              hipStream_t stream) {
  const int*   tok  = (const int*)d_in[0];
  const float* pd   = (const float*)d_in[1];
  const float* lh   = (const float*)d_in[2];
  const float* enc  = (const float*)d_in[3];
  const int*   fiv  = (const int*)d_in[4];
  const float* pa   = (const float*)d_in[5];
  const float* ctrl = (const float*)d_in[6];
  const float* emb  = (const float*)d_in[7];
  const float* W_ih = (const float*)d_in[8];
  const float* W_hh = (const float*)d_in[9];
  const float* b_ih = (const float*)d_in[10];
  const float* b_hh = (const float*)d_in[11];
  const float* w_h  = (const float*)d_in[12];
  const float* w_d  = (const float*)d_in[13];
  const float* gW   = (const float*)d_in[14];
  const float* gb   = (const float*)d_in[15];
  const float* ohW  = (const float*)d_in[16];
  const float* ohb  = (const float*)d_in[17];
  const float* ovW  = (const float*)d_in[18];
  const float* ovb  = (const float*)d_in[19];
  float* out = (float*)d_out;
  float* ws  = (float*)d_ws;

  k_init<<<256, 256, 0, stream>>>(tok, emb, ctrl, ws);
  k_grugemm<<<dim3(48, 5), 256, 0, stream>>>(ws + W_X, lh, W_ih, W_hh, ws);
  k_gates<<<256, 256, 0, stream>>>(ws, lh, b_ih, b_hh, w_h, w_d, ws, out);
  k_den<<<200, 256, 0, stream>>>(pa, ws, out);
  k_escore<<<3200, 256, 0, stream>>>(enc, ws, out);
  k_attdist<<<128, 256, 0, stream>>>(ws, out);
  k_dec<<<128, 256, 0, stream>>>(pd, ws, out);
  k_dhscopy<<<3200, 256, 0, stream>>>(pd, out);
  k_encctx<<<640, 256, 0, stream>>>(enc, out, ws);
  k_outh2<<<dim3(32, 16), 256, 0, stream>>>(ohW, ohb, ws);
  k_gen<<<128, 64, 0, stream>>>(gW, gb, ws, out);
  k_vgemm<<<NBLK, 256, 0, stream>>>(ws + W_LE, ovW, ovb, out + O_PVOCAB, ws);
  k_rowstat2<<<128, 256, 0, stream>>>(ws);
  k_pvocab<<<dim3(49, 128), 256, 0, stream>>>(ws, out);
  k_pad<<<125, 256, 0, stream>>>(out);
  k_scatter<<<200, 256, 0, stream>>>(fiv, out);
}

// Round 6
// 372.399 us; speedup vs baseline: 1.9610x; 1.0384x over previous
//
#include <hip/hip_runtime.h>
#include <hip/hip_bf16.h>
#include <math.h>

// Problem constants
constexpr int B = 128, S = 400, T = 50, H = 512, E = 128, V = 50000, PADV = 1000;
constexpr int NV = V + PADV;        // 51000
constexpr int TH1 = 3 * H + 1;      // 1537
constexpr int NBLK = 391;           // vocab gemm blocks (ceil(50000/128))

// Output offsets (floats), in reference return order
constexpr int O_PFINAL = 0;                      // B*NV
constexpr int O_PGEN   = O_PFINAL + B * NV;      // B
constexpr int O_PVOCAB = O_PGEN + B;             // B*V
constexpr int O_ATT    = O_PVOCAB + B * V;       // B*S
constexpr int O_DHS    = O_ATT + B * S;          // B*(T+1)*H
constexpr int O_H      = O_DHS + B * (T + 1) * H;// B*H
constexpr int O_NPA    = O_H + B * H;            // B*(T+1)*S

// Workspace offsets (floats)
constexpr int W_X    = 0;                  // B*E gathered embedding
constexpr int W_GX   = W_X + B * E;        // B*3H  (raw x@W_ih^T)
constexpr int W_GH   = W_GX + B * 3 * H;   // B*3H  (raw lh@W_hh^T, atomic-accumulated)
constexpr int W_HW   = W_GH + B * 3 * H;   // B*H  (h * w_h)
constexpr int W_HD   = W_HW + B * H;       // B*H  (h * w_d)
constexpr int W_SC   = W_HD + B * H;       // B*S  temporal (exp(score)/den)
constexpr int W_DEN  = W_SC + B * S;       // B*S  temporal denominator
constexpr int W_CMB  = W_DEN + B * S;      // B*TH1 combined
constexpr int W_LE   = W_CMB + B * TH1;    // B*E  logits_e
constexpr int W_RMAX = W_LE + B * E;       // B
constexpr int W_RSUM = W_RMAX + B;         // B
constexpr int W_PM   = W_RSUM + B;         // B*NBLK partial max
constexpr int W_PS   = W_PM + B * NBLK;    // B*NBLK partial sumexp
constexpr int W_ECX  = W_PS + B * NBLK;    // B*H unnormalized encoder context
constexpr int W_TS   = W_ECX + B * H;      // B   sum of temporal over s

__device__ __forceinline__ float wave_sum(float v) {
#pragma unroll
  for (int o = 32; o > 0; o >>= 1) v += __shfl_xor(v, o);
  return v;
}

// ---------------- init: gather emb rows, zero accumulators, set control
__global__ void k_init(const int* __restrict__ tok, const float* __restrict__ emb,
                       const float* __restrict__ ctrl, float* __restrict__ ws) {
  int i = blockIdx.x * 256 + threadIdx.x;   // 65536 threads == B*H
  if (i < B * E) {
    int b = i >> 7, e = i & 127;
    ws[W_X + i] = emb[tok[b] * E + e];
  }
  ws[W_ECX + i] = 0.f;                      // enc-ctx accumulator (B*H)
  if (i < B) {
    ws[W_TS + i] = 0.f;
    ws[W_CMB + i * TH1 + 3 * H] = ctrl[i];
  }
  // zero the gh split-K accumulator (B*3H = 196608 floats, 3 per thread)
#pragma unroll
  for (int j = 0; j < 3; ++j) ws[W_GH + i + j * 65536] = 0.f;
}

// ---------------- fused GRU GEMMs: W_GX = x@W_ih^T (direct), W_GH += lh@W_hh^T (split-K x4)
__global__ __launch_bounds__(256) void k_grugemm(
    const float* __restrict__ x, const float* __restrict__ lh,
    const float* __restrict__ Wih, const float* __restrict__ Whh,
    float* __restrict__ ws) {
  __shared__ float As[32][132];
  __shared__ float Ws[32][36];
  const int tid = threadIdx.x;
  const int n0 = blockIdx.x * 32;
  const int y = blockIdx.y;
  const bool g0 = (y == 0);
  const float* A = g0 ? x : lh;
  const float* W = g0 ? Wih : Whh;
  const int K = g0 ? E : H;
  const int kbase = g0 ? 0 : (y - 1) * 128;
  const int tc = tid & 15;
  const int tr = tid >> 4;
  float acc[8][2] = {};
  for (int c = 0; c < 4; ++c) {
    const int k0 = kbase + c * 32;
    {
      int i = tid;
#pragma unroll
      for (int it = 0; it < 4; ++it, i += 256) {
        int b = i >> 3, k4 = i & 7;
        float4 v = *(const float4*)&A[b * K + k0 + k4 * 4];
        As[k4 * 4 + 0][b] = v.x; As[k4 * 4 + 1][b] = v.y;
        As[k4 * 4 + 2][b] = v.z; As[k4 * 4 + 3][b] = v.w;
      }
    }
    {
      int n = tid >> 3, k4 = tid & 7;
      float4 v = *(const float4*)&W[(n0 + n) * K + k0 + k4 * 4];
      Ws[k4 * 4 + 0][n] = v.x; Ws[k4 * 4 + 1][n] = v.y;
      Ws[k4 * 4 + 2][n] = v.z; Ws[k4 * 4 + 3][n] = v.w;
    }
    __syncthreads();
#pragma unroll
    for (int kk = 0; kk < 32; ++kk) {
      float4 a0 = *(const float4*)&As[kk][tr * 8];
      float4 a1 = *(const float4*)&As[kk][tr * 8 + 4];
      float2 w = *(const float2*)&Ws[kk][tc * 2];
      float av[8] = {a0.x, a0.y, a0.z, a0.w, a1.x, a1.y, a1.z, a1.w};
#pragma unroll
      for (int i = 0; i < 8; ++i) {
        acc[i][0] += av[i] * w.x;
        acc[i][1] += av[i] * w.y;
      }
    }
    __syncthreads();
  }
  if (g0) {
#pragma unroll
    for (int i = 0; i < 8; ++i) {
      float* dst = ws + W_GX + (tr * 8 + i) * (3 * H) + n0 + tc * 2;
      dst[0] = acc[i][0]; dst[1] = acc[i][1];
    }
  } else {
#pragma unroll
    for (int i = 0; i < 8; ++i) {
      float* dst = ws + W_GH + (tr * 8 + i) * (3 * H) + n0 + tc * 2;
      atomicAdd(dst, acc[i][0]); atomicAdd(dst + 1, acc[i][1]);
    }
  }
}

// ---------------- GRU gates -> h, hw, hd, combined[:,0:H], out h slots (adds biases)
__global__ void k_gates(const float* __restrict__ ws_in, const float* __restrict__ lh,
                        const float* __restrict__ bih, const float* __restrict__ bhh,
                        const float* __restrict__ w_h, const float* __restrict__ w_d,
                        float* __restrict__ ws, float* __restrict__ out) {
  int i = blockIdx.x * 256 + threadIdx.x;  // b*H + u
  int b = i >> 9, u = i & 511;
  const float* gx = ws_in + W_GX + b * (3 * H);
  const float* gh = ws_in + W_GH + b * (3 * H);
  float gxr = gx[u] + bih[u], gxz = gx[H + u] + bih[H + u], gxn = gx[2 * H + u] + bih[2 * H + u];
  float ghr = gh[u] + bhh[u], ghz = gh[H + u] + bhh[H + u], ghn = gh[2 * H + u] + bhh[2 * H + u];
  float r = 1.f / (1.f + __expf(-(gxr + ghr)));
  float z = 1.f / (1.f + __expf(-(gxz + ghz)));
  float n = tanhf(gxn + r * ghn);
  float lhv = lh[i];
  float h = (1.f - z) * n + z * lhv;
  out[O_H + i] = h;
  out[O_DHS + b * ((T + 1) * H) + T * H + u] = h;
  ws[W_CMB + b * TH1 + u] = h;
  ws[W_HW + i] = h * w_h[u];
  ws[W_HD + i] = h * w_d[u];
}

// ---------------- temporal denominator + copy previous_att into new_previous_att
__global__ void k_den(const float* __restrict__ pa, float* __restrict__ ws,
                      float* __restrict__ out) {
  int i = blockIdx.x * 256 + threadIdx.x;
  if (i >= B * S) return;
  int b = i / S, s = i - b * S;
  float acc = 0.f;
  for (int t = 0; t < T; ++t) {
    float v = pa[(b * T + t) * S + s];
    out[O_NPA + (b * (T + 1) + t) * S + s] = v;
    acc += __expf(v);
  }
  ws[W_DEN + i] = acc;
}

// ---------------- fused: attention scores + temporal + UNNORMALIZED enc context
// block = (b, sgrp of 16 s), 4 waves x 4 s. enc row reused from registers for ctx.
__global__ void k_escore(const float* __restrict__ enc, float* __restrict__ ws,
                         float* __restrict__ out) {
  __shared__ float ctx[4][512];
  __shared__ float tsw[4];
  int blk = blockIdx.x;             // b*25 + sgrp
  int b = blk / 25, sgrp = blk % 25;
  int tid = threadIdx.x;
  int wave = tid >> 6, lane = tid & 63;
  const float4* hw4 = (const float4*)(ws + W_HW + b * H);
  float4 h0 = hw4[lane * 2], h1 = hw4[lane * 2 + 1];
  float c0[4] = {}, c1[4] = {};
  float tsum = 0.f;
#pragma unroll
  for (int ii = 0; ii < 4; ++ii) {
    int s = sgrp * 16 + wave * 4 + ii;
    const float4* e4 = (const float4*)(enc + (b * S + s) * H);
    float4 e0 = e4[lane * 2], e1 = e4[lane * 2 + 1];
    float d = h0.x * e0.x + h0.y * e0.y + h0.z * e0.z + h0.w * e0.w +
              h1.x * e1.x + h1.y * e1.y + h1.z * e1.z + h1.w * e1.w;
    d = wave_sum(d);                 // all lanes hold the score
    float tmp = __expf(d) / ws[W_DEN + b * S + s];   // temporal (uniform)
    if (lane == 0) {
      ws[W_SC + b * S + s] = tmp;
      out[O_NPA + (b * (T + 1) + T) * S + s] = d;    // raw score row
    }
    tsum += tmp;
    c0[0] += tmp * e0.x; c0[1] += tmp * e0.y; c0[2] += tmp * e0.z; c0[3] += tmp * e0.w;
    c1[0] += tmp * e1.x; c1[1] += tmp * e1.y; c1[2] += tmp * e1.z; c1[3] += tmp * e1.w;
  }
  *(float4*)&ctx[wave][lane * 8]     = make_float4(c0[0], c0[1], c0[2], c0[3]);
  *(float4*)&ctx[wave][lane * 8 + 4] = make_float4(c1[0], c1[1], c1[2], c1[3]);
  if (lane == 0) tsw[wave] = tsum;
  __syncthreads();
  for (int h = tid; h < H; h += 256) {
    float v = ctx[0][h] + ctx[1][h] + ctx[2][h] + ctx[3][h];
    atomicAdd(&ws[W_ECX + b * H + h], v);
  }
  if (tid == 0) atomicAdd(&ws[W_TS + b], tsw[0] + tsw[1] + tsw[2] + tsw[3]);
}

// ---------------- normalize: att_dist + encoder-context slice of combined (block per b)
__global__ void k_attdist(const float* __restrict__ ws_in, float* __restrict__ ws,
                          float* __restrict__ out) {
  int b = blockIdx.x, tid = threadIdx.x;
  float inv = 1.f / ws_in[W_TS + b];
  int s0 = tid, s1 = tid + 256;
  out[O_ATT + b * S + s0] = ws_in[W_SC + b * S + s0] * inv;
  if (s1 < S) out[O_ATT + b * S + s1] = ws_in[W_SC + b * S + s1] * inv;
  for (int h = tid; h < H; h += 256)
    ws[W_CMB + b * TH1 + H + h] = ws_in[W_ECX + b * H + h] * inv;
}

// ---------------- decoder attention: scores, softmax, context
__global__ void k_dec(const float* __restrict__ pd, float* __restrict__ ws,
                      float* __restrict__ out) {
  int b = blockIdx.x, tid = threadIdx.x;
  int wave = tid >> 6, lane = tid & 63;
  __shared__ float sc[T];
  const float4* hd4 = (const float4*)(ws + W_HD + b * H);
  float4 d0 = hd4[lane * 2], d1 = hd4[lane * 2 + 1];
  for (int t = wave; t < T; t += 4) {
    const float4* p4 = (const float4*)(pd + (b * T + t) * H);
    float4 p0 = p4[lane * 2], p1 = p4[lane * 2 + 1];
    float v = d0.x * p0.x + d0.y * p0.y + d0.z * p0.z + d0.w * p0.w +
              d1.x * p1.x + d1.y * p1.y + d1.z * p1.z + d1.w * p1.w;
    v = wave_sum(v);
    if (lane == 0) sc[t] = v;
  }
  __syncthreads();
  if (tid < 64) {
    float v = (lane < T) ? sc[lane] : -1e30f;
    float m = v;
#pragma unroll
    for (int o = 32; o > 0; o >>= 1) m = fmaxf(m, __shfl_xor(m, o));
    float e = (lane < T) ? __expf(v - m) : 0.f;
    float ssum = wave_sum(e);
    if (lane < T) sc[lane] = e / ssum;
  }
  __syncthreads();
  float a0 = 0.f, a1 = 0.f;
  int h0 = tid, h1 = tid + 256;
  for (int t = 0; t < T; ++t) {
    float wt = sc[t];
    a0 += wt * pd[(b * T + t) * H + h0];
    a1 += wt * pd[(b * T + t) * H + h1];
  }
  ws[W_CMB + b * TH1 + 2 * H + h0] = a0;
  ws[W_CMB + b * TH1 + 2 * H + h1] = a1;
}

// ---------------- flat copy of prev decoder states into decoder_h_states rows [0..T)
__global__ void k_dhscopy(const float* __restrict__ pd, float* __restrict__ out) {
  int i = blockIdx.x * 256 + threadIdx.x;      // float4 index over B*T*H/4
  if (i >= B * T * H / 4) return;
  int b = i / (T * H / 4), rem = i - b * (T * H / 4);
  ((float4*)(out + O_DHS + b * (T + 1) * H))[rem] = ((const float4*)(pd + b * T * H))[rem];
}

// ---------------- logits_e = combined @ outh_W^T + outh_b
__global__ __launch_bounds__(256) void k_outh2(const float* __restrict__ oW,
                                               const float* __restrict__ ob,
                                               float* __restrict__ ws) {
  __shared__ float cmb[8 * TH1];
  const int tid = threadIdx.x;
  const int b0 = blockIdx.y * 8;
  const int e = blockIdx.x * 4 + (tid >> 6);
  const int lane = tid & 63;
  const float* src = ws + W_CMB + b0 * TH1;
  for (int i = tid; i < 8 * TH1; i += 256) cmb[i] = src[i];
  float wr[25];
  const float* wrow = oW + e * TH1;
#pragma unroll
  for (int j = 0; j < 25; ++j) {
    int k = lane + 64 * j;
    wr[j] = (k < TH1) ? wrow[k] : 0.f;
  }
  __syncthreads();
  float bias = ob[e];
#pragma unroll 1
  for (int bb = 0; bb < 8; ++bb) {
    const float* c = cmb + bb * TH1;
    float a = 0.f;
#pragma unroll
    for (int j = 0; j < 25; ++j) {
      int k = lane + 64 * j;
      float cv = (k < TH1) ? c[k] : 0.f;
      a += wr[j] * cv;
    }
    a = wave_sum(a);
    if (lane == 0) ws[W_LE + (b0 + bb) * E + e] = a + bias;
  }
}

// ---------------- p_gen (one wave per b)
__global__ void k_gen(const float* __restrict__ gW, const float* __restrict__ gb,
                      const float* __restrict__ ws, float* __restrict__ out) {
  int b = blockIdx.x, lane = threadIdx.x;
  float acc = 0.f;
  for (int k = lane; k < TH1; k += 64) acc += gW[k] * ws[W_CMB + b * TH1 + k];
  acc = wave_sum(acc);
  if (lane == 0) out[O_PGEN + b] = 1.f / (1.f + __expf(-(acc + gb[0])));
}

// ---------------- vocab GEMM: C[128][V] = A[128][128] @ W[V][128]^T + bias
// 8x8 register tile, fused per-block row max/sumexp partials.
__global__ __launch_bounds__(256) void k_vgemm(
    const float* __restrict__ A, const float* __restrict__ W,
    const float* __restrict__ bias, float* __restrict__ C,
    float* __restrict__ ws) {
  __shared__ float As[32][132];
  __shared__ float Bs[32][132];
  const int tid = threadIdx.x;
  const int n0 = blockIdx.x * 128;
  const int tr = tid >> 4;        // rows tr*8..+7
  const int tc = tid & 15;        // cols tc*8..+7
  float acc[8][8] = {};
#pragma unroll 1
  for (int c = 0; c < 4; ++c) {
    const int k0 = c * 32;
    {
      int i = tid;
#pragma unroll
      for (int it = 0; it < 4; ++it, i += 256) {
        int m = i >> 3, k4 = i & 7;
        float4 v = *(const float4*)&A[m * 128 + k0 + k4 * 4];
        As[k4 * 4 + 0][m] = v.x; As[k4 * 4 + 1][m] = v.y;
        As[k4 * 4 + 2][m] = v.z; As[k4 * 4 + 3][m] = v.w;
      }
    }
    {
      int i = tid;
#pragma unroll
      for (int it = 0; it < 4; ++it, i += 256) {
        int n = i >> 3, k4 = i & 7;
        float4 v = make_float4(0.f, 0.f, 0.f, 0.f);
        if (n0 + n < V) v = *(const float4*)&W[(n0 + n) * 128 + k0 + k4 * 4];
        Bs[k4 * 4 + 0][n] = v.x; Bs[k4 * 4 + 1][n] = v.y;
        Bs[k4 * 4 + 2][n] = v.z; Bs[k4 * 4 + 3][n] = v.w;
      }
    }
    __syncthreads();
#pragma unroll 4
    for (int kk = 0; kk < 32; ++kk) {
      float4 a0 = *(const float4*)&As[kk][tr * 8];
      float4 a1 = *(const float4*)&As[kk][tr * 8 + 4];
      float4 b0 = *(const float4*)&Bs[kk][tc * 8];
      float4 b1 = *(const float4*)&Bs[kk][tc * 8 + 4];
      float av[8] = {a0.x, a0.y, a0.z, a0.w, a1.x, a1.y, a1.z, a1.w};
      float bw[8] = {b0.x, b0.y, b0.z, b0.w, b1.x, b1.y, b1.z, b1.w};
#pragma unroll
      for (int i = 0; i < 8; ++i)
#pragma unroll
        for (int j = 0; j < 8; ++j) acc[i][j] += av[i] * bw[j];
    }
    __syncthreads();
  }
  const int cbase = n0 + tc * 8;
  float bv[8];
#pragma unroll
  for (int j = 0; j < 8; ++j) bv[j] = (cbase + j < V) ? bias[cbase + j] : 0.f;
#pragma unroll
  for (int i = 0; i < 8; ++i) {
    int r = tr * 8 + i;
    float m = -1e30f;
#pragma unroll
    for (int j = 0; j < 8; ++j) {
      acc[i][j] += bv[j];
      if (cbase + j < V) m = fmaxf(m, acc[i][j]);
    }
#pragma unroll
    for (int o = 1; o < 16; o <<= 1) m = fmaxf(m, __shfl_xor(m, o));
    float s = 0.f;
#pragma unroll
    for (int j = 0; j < 8; ++j)
      if (cbase + j < V) s += __expf(acc[i][j] - m);
#pragma unroll
    for (int o = 1; o < 16; o <<= 1) s += __shfl_xor(s, o);
    if (tc == 0) {
      ws[W_PM + r * NBLK + blockIdx.x] = m;
      ws[W_PS + r * NBLK + blockIdx.x] = s;
    }
    if (cbase + 8 <= V) {
      *(float4*)&C[r * V + cbase] = make_float4(acc[i][0], acc[i][1], acc[i][2], acc[i][3]);
      *(float4*)&C[r * V + cbase + 4] = make_float4(acc[i][4], acc[i][5], acc[i][6], acc[i][7]);
    } else {
#pragma unroll
      for (int j = 0; j < 8; ++j)
        if (cbase + j < V) C[r * V + cbase + j] = acc[i][j];
    }
  }
}

// ---------------- combine NBLK partials per row (block per b)
__global__ void k_rowstat2(float* __restrict__ ws) {
  int b = blockIdx.x, tid = threadIdx.x;
  const float* pm = ws + W_PM + b * NBLK;
  const float* psv = ws + W_PS + b * NBLK;
  __shared__ float red[4];
  float m = -1e30f;
  for (int c = tid; c < NBLK; c += 256) m = fmaxf(m, pm[c]);
#pragma unroll
  for (int o = 32; o > 0; o >>= 1) m = fmaxf(m, __shfl_xor(m, o));
  if ((tid & 63) == 0) red[tid >> 6] = m;
  __syncthreads();
  float M = fmaxf(fmaxf(red[0], red[1]), fmaxf(red[2], red[3]));
  __syncthreads();
  float s = 0.f;
  for (int c = tid; c < NBLK; c += 256) s += psv[c] * __expf(pm[c] - M);
  s = wave_sum(s);
  if ((tid & 63) == 0) red[tid >> 6] = s;
  __syncthreads();
  if (tid == 0) {
    ws[W_RMAX + b] = M;
    ws[W_RSUM + b] = red[0] + red[1] + red[2] + red[3];
  }
}

// ---------------- vocab softmax pass 2: p_vocab + p_final (incl. zeroing pad region)
__global__ void k_pvocab(const float* __restrict__ ws, float* __restrict__ out) {
  int b = blockIdx.y;
  int i = blockIdx.x * 256 + threadIdx.x;    // float4 index, grid covers NV/4 = 12750
  if (i >= NV / 4) return;
  if (i >= V / 4) {                          // pad region [V, NV)
    ((float4*)(out + O_PFINAL + b * NV))[i] = make_float4(0.f, 0.f, 0.f, 0.f);
    return;
  }
  float m = ws[W_RMAX + b], inv = 1.f / ws[W_RSUM + b];
  float pg = out[O_PGEN + b];
  float4 v = ((const float4*)(out + O_PVOCAB + b * V))[i];
  float4 p;
  p.x = __expf(v.x - m) * inv;
  p.y = __expf(v.y - m) * inv;
  p.z = __expf(v.z - m) * inv;
  p.w = __expf(v.w - m) * inv;
  ((float4*)(out + O_PVOCAB + b * V))[i] = p;
  float4 pf;
  pf.x = pg * p.x; pf.y = pg * p.y; pf.z = pg * p.z; pf.w = pg * p.w;
  ((float4*)(out + O_PFINAL + b * NV))[i] = pf;
}

// ---------------- scatter (1-p_gen)*att_dist into p_final
__global__ void k_scatter(const int* __restrict__ fiv, float* __restrict__ out) {
  int i = blockIdx.x * 256 + threadIdx.x;
  if (i >= B * S) return;
  int b = i / S;
  int idx = fiv[i];
  float pg = out[O_PGEN + b];
  float val = (1.f - pg) * out[O_ATT + i];
  atomicAdd(out + O_PFINAL + b * NV + idx, val);
}

extern "C" void kernel_launch(void* const* d_in, const int* in_sizes, int n_in,
                              void* d_out, int out_size, void* d_ws, size_t ws_size,
                              hipStream_t stream) {
  const int*   tok  = (const int*)d_in[0];
  const float* pd   = (const float*)d_in[1];
  const float* lh   = (const float*)d_in[2];
  const float* enc  = (const float*)d_in[3];
  const int*   fiv  = (const int*)d_in[4];
  const float* pa   = (const float*)d_in[5];
  const float* ctrl = (const float*)d_in[6];
  const float* emb  = (const float*)d_in[7];
  const float* W_ih = (const float*)d_in[8];
  const float* W_hh = (const float*)d_in[9];
  const float* b_ih = (const float*)d_in[10];
  const float* b_hh = (const float*)d_in[11];
  const float* w_h  = (const float*)d_in[12];
  const float* w_d  = (const float*)d_in[13];
  const float* gW   = (const float*)d_in[14];
  const float* gb   = (const float*)d_in[15];
  const float* ohW  = (const float*)d_in[16];
  const float* ohb  = (const float*)d_in[17];
  const float* ovW  = (const float*)d_in[18];
  const float* ovb  = (const float*)d_in[19];
  float* out = (float*)d_out;
  float* ws  = (float*)d_ws;

  k_init<<<256, 256, 0, stream>>>(tok, emb, ctrl, ws);
  k_grugemm<<<dim3(48, 5), 256, 0, stream>>>(ws + W_X, lh, W_ih, W_hh, ws);
  k_gates<<<256, 256, 0, stream>>>(ws, lh, b_ih, b_hh, w_h, w_d, ws, out);
  k_den<<<200, 256, 0, stream>>>(pa, ws, out);
  k_escore<<<3200, 256, 0, stream>>>(enc, ws, out);
  k_attdist<<<128, 256, 0, stream>>>(ws, ws, out);
  k_dec<<<128, 256, 0, stream>>>(pd, ws, out);
  k_dhscopy<<<3200, 256, 0, stream>>>(pd, out);
  k_outh2<<<dim3(32, 16), 256, 0, stream>>>(ohW, ohb, ws);
  k_gen<<<128, 64, 0, stream>>>(gW, gb, ws, out);
  k_vgemm<<<NBLK, 256, 0, stream>>>(ws + W_LE, ovW, ovb, out + O_PVOCAB, ws);
  k_rowstat2<<<128, 256, 0, stream>>>(ws);
  k_pvocab<<<dim3(50, 128), 256, 0, stream>>>(ws, out);
  k_scatter<<<200, 256, 0, stream>>>(fiv, out);
}